// Round 11
// baseline (25401.744 us; speedup 1.0000x reference)
//
#include <hip/hip_runtime.h>
#include <hip/hip_bf16.h>
#include <math.h>

#define DEV __device__ __forceinline__

typedef __attribute__((ext_vector_type(8))) short s16x8;   // 8 bf16 in 4 VGPRs
typedef __attribute__((ext_vector_type(4))) float f32x4;

// ELU matching numpy (encoder only): f64 expm1 + single f32 round.
DEV float elu_f(float v) { return v > 0.0f ? v : (float)expm1((double)v); }
// fast f32 ELU (decoder epilogue; accuracy uncritical)
DEV float elu_fast(float v) { return v > 0.0f ? v : expm1f(v); }

DEV unsigned short f2bf(float f) {
  unsigned u = __float_as_uint(f);
  return (unsigned short)((u + 0x7fffu + ((u >> 16) & 1u)) >> 16);
}
DEV float bf2f(unsigned short s) { return __uint_as_float(((unsigned)s) << 16); }

constexpr int ceil_div_c(int a, int b) { return (a > 0) ? (a + b - 1) / b : -((-a) / b); }

// ---------------------------------------------------------------------------
// f32 forward conv1d, LDS-staged x (encoder — BIT-EXACT: per output the FMA
// chain is sequential (ci outer, k inner), identical to rounds 4-10 passing
// kernels; only WHERE x is read from changed: block-shared LDS instead of
// per-wave global loads).
//  * block = 256 = 4 waves; wave -> 4 co (16 co/block); thread -> 8 outputs;
//    all 4 waves share one t-range -> x staged ONCE per block per ci-chunk.
//  * XOR swizzle a^=((a>>7)&3)<<4 on byte addresses (both sides, involutive):
//    spreads lane strides 64B/32B so every 8-lane group covers all 32 banks.
//  * bounds checks only in staging; compute loop is branch-free.
// ---------------------------------------------------------------------------
template<int K, int S, int PAD, int ACT, int CC>
__global__ __launch_bounds__(256) void conv1d_k(
    const float* __restrict__ x, const float* __restrict__ w,
    const float* __restrict__ bias, float* __restrict__ y,
    int Cin, int Cout, int Lin, int Lout)
{
  constexpr int PT = 8;
  constexpr int W  = (PT - 1) * S + K;         // per-lane window (floats)
  constexpr int NR = (W + 3) / 4;              // b128 reads per lane per ci
  constexpr int RS = 63 * PT * S + NR * 4;     // LDS row size (floats)
  constexpr int KP = (K + 3) & ~3;

  const int lane = threadIdx.x & 63;
  const int wv   = threadIdx.x >> 6;
  const int b    = blockIdx.z;
  const int cob  = blockIdx.y * 16;
  const int T0   = blockIdx.x * 512;           // block's first output t
  const int t0   = T0 + lane * PT;

  __shared__ __align__(16) float xs[CC * RS];
  __shared__ __align__(16) float wl[16][CC][KP];

  float acc[4][PT];
  #pragma unroll
  for (int cc = 0; cc < 4; ++cc)
    #pragma unroll
    for (int g = 0; g < PT; ++g) acc[cc][g] = 0.0f;

  const float* xb = x + (size_t)b * Cin * Lin;
  const int G0 = T0 * S - PAD;                 // LDS pos t holds x[G0 + t]

  for (int c0 = 0; c0 < Cin; c0 += CC) {
    const int cn = (Cin - c0 < CC) ? (Cin - c0) : CC;
    __syncthreads();
    // ---- stage x rows (scalar, coalesced, bounds-checked, swizzled) ----
    for (int i = threadIdx.x; i < cn * RS; i += 256) {
      int r = i / RS, t = i - r * RS;
      int gi = G0 + t;
      float v = (gi >= 0 && gi < Lin) ? xb[(size_t)(c0 + r) * Lin + gi] : 0.0f;
      int a = (r * RS + t) * 4;
      a ^= ((a >> 7) & 3) << 4;
      *(float*)((char*)xs + a) = v;
    }
    // ---- stage weights ----
    for (int i = threadIdx.x; i < 16 * cn * K; i += 256) {
      int cc  = i / (cn * K);
      int rem = i - cc * (cn * K);
      int ci  = rem / K;
      int k   = rem - ci * K;
      wl[cc][ci][k] = w[((size_t)(cob + cc) * Cin + (c0 + ci)) * K + k];
    }
    __syncthreads();
    // ---- compute ----
    #pragma unroll 1
    for (int ci = 0; ci < cn; ++ci) {
      float xr[4 * NR];
      const int rb = ci * (RS * 4);
      #pragma unroll
      for (int jj = 0; jj < NR; ++jj) {
        int a = rb + lane * (PT * S * 4) + jj * 16;
        a ^= ((a >> 7) & 3) << 4;
        float4 t = *(const float4*)((const char*)xs + a);
        xr[4*jj+0] = t.x; xr[4*jj+1] = t.y; xr[4*jj+2] = t.z; xr[4*jj+3] = t.w;
      }
      #pragma unroll
      for (int cc = 0; cc < 4; ++cc) {
        float wk[KP];
        const float4* wq4 = (const float4*)(&wl[wv * 4 + cc][ci][0]);
        #pragma unroll
        for (int q4 = 0; q4 < KP / 4; ++q4) {
          float4 t = wq4[q4];
          wk[4*q4+0] = t.x; wk[4*q4+1] = t.y; wk[4*q4+2] = t.z; wk[4*q4+3] = t.w;
        }
        #pragma unroll
        for (int k = 0; k < K; ++k) {
          const float wv_ = wk[k];
          #pragma unroll
          for (int g = 0; g < PT; ++g)
            acc[cc][g] = fmaf(wv_, xr[g * S + k], acc[cc][g]);  // seq (ci,k)
        }
      }
    }
  }

  #pragma unroll
  for (int cc = 0; cc < 4; ++cc) {
    const int co = cob + wv * 4 + cc;
    const float bv = bias[co];
    float res[PT];
    #pragma unroll
    for (int g = 0; g < PT; ++g) {
      float v = acc[cc][g] + bv;
      if (ACT == 1) v = elu_f(v);
      res[g] = v;
    }
    float* yp = y + ((size_t)b * Cout + co) * Lout + t0;
    *(float4*)(yp)     = make_float4(res[0], res[1], res[2], res[3]);
    *(float4*)(yp + 4) = make_float4(res[4], res[5], res[6], res[7]);
  }
}

// ---------------------------------------------------------------------------
// Batched 2D transpose: in (B, R, S) -> out (B, S, R).
// ---------------------------------------------------------------------------
__global__ __launch_bounds__(256) void transpose_k(
    const float* __restrict__ in, float* __restrict__ out, int R, int S_)
{
  __shared__ float tile[32][33];
  const int b  = blockIdx.z;
  const int r0 = blockIdx.y * 32;
  const int s0 = blockIdx.x * 32;
  const float* ib = in + (size_t)b * R * S_;
  float* ob = out + (size_t)b * R * S_;
  const int tx = threadIdx.x, ty = threadIdx.y;
  #pragma unroll
  for (int i = 0; i < 32; i += 8)
    tile[ty + i][tx] = ib[(size_t)(r0 + ty + i) * S_ + s0 + tx];
  __syncthreads();
  #pragma unroll
  for (int i = 0; i < 32; i += 8)
    ob[(size_t)(s0 + ty + i) * R + r0 + tx] = tile[tx][ty + i];
}

// ---------------------------------------------------------------------------
// numpy-pairwise-identical f32 sum of squares over 512 contiguous floats.
// ---------------------------------------------------------------------------
DEV float np_sumsq_128(const float* a) {
  float r[8];
  #pragma unroll
  for (int j = 0; j < 8; ++j) r[j] = __fmul_rn(a[j], a[j]);
  #pragma unroll
  for (int i = 8; i < 128; i += 8) {
    #pragma unroll
    for (int j = 0; j < 8; ++j)
      r[j] = __fadd_rn(r[j], __fmul_rn(a[i + j], a[i + j]));
  }
  float s01 = __fadd_rn(r[0], r[1]), s23 = __fadd_rn(r[2], r[3]);
  float s45 = __fadd_rn(r[4], r[5]), s67 = __fadd_rn(r[6], r[7]);
  return __fadd_rn(__fadd_rn(s01, s23), __fadd_rn(s45, s67));
}
DEV float np_sumsq_512(const float* a) {
  float s0 = np_sumsq_128(a);
  float s1 = np_sumsq_128(a + 128);
  float s2 = np_sumsq_128(a + 256);
  float s3 = np_sumsq_128(a + 384);
  return __fadd_rn(__fadd_rn(s0, s1), __fadd_rn(s2, s3));
}

__global__ __launch_bounds__(256) void rowsumsq_k(
    const float* __restrict__ in, float* __restrict__ out, int nrows)
{
  const int r = blockIdx.x * 256 + threadIdx.x;
  if (r >= nrows) return;
  out[r] = np_sumsq_512(in + (size_t)r * 512);
}

// ---------------------------------------------------------------------------
// VQ, numpy-f32-faithful (BIT-EXACT — do not change).
// ---------------------------------------------------------------------------
__global__ __launch_bounds__(256) void vq_k(
    const float* __restrict__ embT, const float* __restrict__ cb,
    const float* __restrict__ t1, const float* __restrict__ cnorm,
    float* __restrict__ qout, float* __restrict__ codes, float* __restrict__ pc)
{
  __shared__ __align__(16) float xs[8][512];
  __shared__ float rv[4][8];
  __shared__ int   ri[4][8];
  __shared__ int   bidx[8];
  __shared__ float cred[4];

  const int tid  = threadIdx.x;
  const int row0 = blockIdx.x * 8;

  for (int i = tid * 4; i < 4096; i += 1024)
    *(float4*)((float*)xs + i) = *(const float4*)(embT + (size_t)row0 * 512 + i);
  __syncthreads();

  float acc[4][8];
  #pragma unroll
  for (int j = 0; j < 4; ++j)
    #pragma unroll
    for (int r = 0; r < 8; ++r) acc[j][r] = 0.0f;

  const float* cbp = cb + (size_t)tid * 512;
  #pragma unroll 1
  for (int d0 = 0; d0 < 512; d0 += 4) {
    float4 xv[8];
    #pragma unroll
    for (int r = 0; r < 8; ++r) xv[r] = *(const float4*)&xs[r][d0];
    #pragma unroll
    for (int j = 0; j < 4; ++j) {
      float4 cv = *(const float4*)(cbp + (size_t)j * 256 * 512 + d0);
      #pragma unroll
      for (int r = 0; r < 8; ++r) {
        acc[j][r] = fmaf(cv.x, xv[r].x, acc[j][r]);
        acc[j][r] = fmaf(cv.y, xv[r].y, acc[j][r]);
        acc[j][r] = fmaf(cv.z, xv[r].z, acc[j][r]);
        acc[j][r] = fmaf(cv.w, xv[r].w, acc[j][r]);
      }
    }
  }

  float cnj[4];
  #pragma unroll
  for (int j = 0; j < 4; ++j) cnj[j] = cnorm[tid + 256 * j];
  float t1r[8];
  #pragma unroll
  for (int r = 0; r < 8; ++r) t1r[r] = t1[row0 + r];

  const int lane = tid & 63, wv = tid >> 6;
  #pragma unroll 1
  for (int r = 0; r < 8; ++r) {
    float bv = 0.0f; int bi = 0;
    #pragma unroll
    for (int j = 0; j < 4; ++j) {
      float dv = __fsub_rn(__fadd_rn(t1r[r], cnj[j]), __fmul_rn(2.0f, acc[j][r]));
      int ki = tid + 256 * j;
      if (j == 0 || dv < bv || (dv == bv && ki < bi)) { bv = dv; bi = ki; }
    }
    #pragma unroll
    for (int off = 32; off; off >>= 1) {
      float ov = __shfl_xor(bv, off);
      int   oi = __shfl_xor(bi, off);
      if (ov < bv || (ov == bv && oi < bi)) { bv = ov; bi = oi; }
    }
    if (lane == 0) { rv[wv][r] = bv; ri[wv][r] = bi; }
  }
  __syncthreads();
  if (tid < 8) {
    float bv = rv[0][tid]; int bi = ri[0][tid];
    #pragma unroll
    for (int wq = 1; wq < 4; ++wq) {
      float ov = rv[wq][tid]; int oi = ri[wq][tid];
      if (ov < bv || (ov == bv && oi < bi)) { bv = ov; bi = oi; }
    }
    bidx[tid] = bi;
    codes[row0 + tid] = (float)bi;
  }
  __syncthreads();

  float csum = 0.0f;
  for (int i = tid * 4; i < 4096; i += 1024) {
    int r = i >> 9, d = i & 511;
    float4 qv = *(const float4*)(cb + (size_t)bidx[r] * 512 + d);
    *(float4*)(qout + (size_t)(row0 + r) * 512 + d) = qv;
    float dx = qv.x - xs[r][d],     dy = qv.y - xs[r][d + 1];
    float dz = qv.z - xs[r][d + 2], dw = qv.w - xs[r][d + 3];
    csum += dx * dx + dy * dy + dz * dz + dw * dw;
  }
  #pragma unroll
  for (int off = 32; off; off >>= 1) csum += __shfl_xor(csum, off);
  if (lane == 0) cred[wv] = csum;
  __syncthreads();
  if (tid == 0) pc[blockIdx.x] = cred[0] + cred[1] + cred[2] + cred[3];
}

// ---------------------------------------------------------------------------
// f32 -> bf16 elementwise (4/thread)
// ---------------------------------------------------------------------------
__global__ __launch_bounds__(256) void f32_to_bf16_k(
    const float* __restrict__ in, unsigned short* __restrict__ out, int n4)
{
  int i = blockIdx.x * 256 + threadIdx.x;
  if (i >= n4) return;
  float4 v = *(const float4*)(in + (size_t)i * 4);
  ushort4 o;
  o.x = f2bf(v.x); o.y = f2bf(v.y); o.z = f2bf(v.z); o.w = f2bf(v.w);
  *(ushort4*)(out + (size_t)i * 4) = o;
}

__global__ __launch_bounds__(256) void zero_zbuf_k(unsigned short* z) {
  z[blockIdx.x * 256 + threadIdx.x] = 0;
}

// ---------------------------------------------------------------------------
// Decoder weight prepack: w [Cin][Cout][K] f32 -> wp bf16 (B-frag contiguous).
// ---------------------------------------------------------------------------
__global__ __launch_bounds__(256) void prepack_w_k(
    const float* __restrict__ w, unsigned short* __restrict__ wp,
    int Cin, int Cout, int K, int T, int m0, int ms)
{
  int id = blockIdx.x * 256 + threadIdx.x;
  int tot = T * Cin * Cout;
  if (id >= tot) return;
  int jj  = id / (Cin * Cout);
  int rem = id - jj * (Cin * Cout);
  int ci  = rem / Cout;
  int co  = rem - ci * Cout;
  int m   = m0 + ms * jj;
  float v = w[((size_t)ci * Cout + co) * K + m];
  size_t dst = ((size_t)((jj * (Cin >> 5) + (ci >> 5)) * 4 + ((ci & 31) >> 3))) * ((size_t)Cout * 8)
             + (size_t)co * 8 + (ci & 7);
  wp[dst] = f2bf(v);
}

// ---------------------------------------------------------------------------
// MFMA implicit-GEMM transposed-conv (one parity): bf16 in/out, f32 accum.
// ---------------------------------------------------------------------------
__global__ __launch_bounds__(256) void mfma_convt_k(
    const unsigned short* __restrict__ xb, const unsigned short* __restrict__ wp,
    const float* __restrict__ bias, unsigned short* __restrict__ yb,
    const unsigned short* __restrict__ zbuf,
    int Cin, int Cout, int Lin, int Lout, int S, int p, int T, int OFF0)
{
  const int lane = threadIdx.x & 63;
  const int wv   = threadIdx.x >> 6;
  const int r    = lane & 15;
  const int g    = lane >> 4;
  const int b    = blockIdx.z;
  const int u0   = blockIdx.x * 64 + wv * 16;
  const int co0  = blockIdx.y * 16;
  const int CB   = Cin >> 5;

  f32x4 acc = {0.f, 0.f, 0.f, 0.f};
  const unsigned short* xbb = xb + (size_t)b * Lin * Cin + g * 8;
  const unsigned short* zp  = zbuf + g * 8;
  const unsigned short* wpb = wp + (size_t)(co0 + r) * 8 + (size_t)g * Cout * 8;
  const size_t bstride = (size_t)4 * Cout * 8;

  const float bv = bias[co0 + r];

  #pragma unroll 1
  for (int jj = 0; jj < T; ++jj) {
    int u = u0 + r + OFF0 - jj;
    bool val = (u >= 0) && (u < Lin);
    const unsigned short* ap = val ? (xbb + (size_t)u * Cin) : zp;
    const unsigned short* bp = wpb + (size_t)jj * CB * bstride;
    #pragma unroll 2
    for (int cb = 0; cb < CB; ++cb) {
      s16x8 a  = *(const s16x8*)(ap + cb * 32);
      s16x8 bf = *(const s16x8*)(bp + (size_t)cb * bstride);
      acc = __builtin_amdgcn_mfma_f32_16x16x32_bf16(a, bf, acc, 0, 0, 0);
    }
  }

  #pragma unroll
  for (int reg = 0; reg < 4; ++reg) {
    int u  = u0 + g * 4 + reg;
    int o  = S * u + p;
    float v = elu_fast(acc[reg] + bv);
    yb[((size_t)b * Lout + o) * Cout + (co0 + r)] = f2bf(v);
  }
}

// ---------------------------------------------------------------------------
// Final decoder layer from bf16 row-major input [B][65536][64]: tanh conv.
// ---------------------------------------------------------------------------
__global__ __launch_bounds__(256) void convt_final_bf16_k(
    const unsigned short* __restrict__ xb, const float* __restrict__ w,
    const float* __restrict__ bias, float* __restrict__ y)
{
  __shared__ float wl[64][16];
  for (int i = threadIdx.x; i < 64 * 15; i += 256) wl[i / 15][i % 15] = w[i];
  __syncthreads();
  const int b = blockIdx.y;
  const int o = blockIdx.x * 256 + threadIdx.x;
  float acc = 0.0f;
  #pragma unroll 1
  for (int m = 0; m < 15; ++m) {
    int i = o + 7 - m;
    if (i < 0 || i >= 65536) continue;
    const unsigned short* xp = xb + ((size_t)b * 65536 + i) * 64;
    #pragma unroll
    for (int c8 = 0; c8 < 8; ++c8) {
      s16x8 xv = *(const s16x8*)(xp + c8 * 8);
      #pragma unroll
      for (int k = 0; k < 8; ++k)
        acc = fmaf(wl[c8 * 8 + k][m], bf2f((unsigned short)xv[k]), acc);
    }
  }
  y[(size_t)b * 65536 + o] = tanhf(acc + bias[0]);
}

// ---------------------------------------------------------------------------
// recon |diff| partial reduce + final losses
// ---------------------------------------------------------------------------
__global__ __launch_bounds__(256) void absdiff_part_k(
    const float* __restrict__ a, const float* __restrict__ b, float* __restrict__ pr)
{
  __shared__ float cred[4];
  const int tid  = threadIdx.x;
  const int base = blockIdx.x * 2048;
  float s = 0.0f;
  for (int i = tid * 4; i < 2048; i += 1024) {
    float4 x = *(const float4*)(a + base + i);
    float4 y = *(const float4*)(b + base + i);
    s += fabsf(x.x - y.x) + fabsf(x.y - y.y) + fabsf(x.z - y.z) + fabsf(x.w - y.w);
  }
  #pragma unroll
  for (int off = 32; off; off >>= 1) s += __shfl_xor(s, off);
  const int lane = tid & 63, wv = tid >> 6;
  if (lane == 0) cred[wv] = s;
  __syncthreads();
  if (tid == 0) pr[blockIdx.x] = cred[0] + cred[1] + cred[2] + cred[3];
}

__global__ __launch_bounds__(256) void finalize_k(
    const float* __restrict__ pc, const float* __restrict__ pr, float* __restrict__ outp)
{
  __shared__ float red[4];
  const int tid = threadIdx.x;
  const int lane = tid & 63, wv = tid >> 6;

  float s = 0.0f;
  for (int i = tid; i < 8192; i += 256) s += pc[i];
  #pragma unroll
  for (int off = 32; off; off >>= 1) s += __shfl_xor(s, off);
  if (lane == 0) red[wv] = s;
  __syncthreads();
  if (tid == 0) outp[0] = 0.25f * (red[0] + red[1] + red[2] + red[3]) / 33554432.0f;
  __syncthreads();

  float s2 = 0.0f;
  if (tid < 64) {
    for (int i = tid; i < 256; i += 64) s2 += pr[i];
    #pragma unroll
    for (int off = 32; off; off >>= 1) s2 += __shfl_xor(s2, off);
    if (tid == 0) outp[1] = s2 / 524288.0f;
  }
}

// ---------------------------------------------------------------------------
extern "C" void kernel_launch(void* const* d_in, const int* in_sizes, int n_in,
                              void* d_out, int out_size, void* d_ws, size_t ws_size,
                              hipStream_t stream) {
  const float* wave = (const float*)d_in[0];
  const float* e1w = (const float*)d_in[1];  const float* e1b = (const float*)d_in[2];
  const float* e2w = (const float*)d_in[3];  const float* e2b = (const float*)d_in[4];
  const float* e3w = (const float*)d_in[5];  const float* e3b = (const float*)d_in[6];
  const float* e4w = (const float*)d_in[7];  const float* e4b = (const float*)d_in[8];
  const float* e5w = (const float*)d_in[9];  const float* e5b = (const float*)d_in[10];
  const float* cb  = (const float*)d_in[11];
  const float* d1w = (const float*)d_in[12]; const float* d1b = (const float*)d_in[13];
  const float* d2w = (const float*)d_in[14]; const float* d2b = (const float*)d_in[15];
  const float* d3w = (const float*)d_in[16]; const float* d3b = (const float*)d_in[17];
  const float* d4w = (const float*)d_in[18]; const float* d4b = (const float*)d_in[19];
  const float* d5w = (const float*)d_in[20]; const float* d5b = (const float*)d_in[21];

  float* out = (float*)d_out;
  float* recon  = out;                   // (8, 65536)
  float* qout   = out + 524288;          // (8, 8192, 512)
  float* codes  = out + 34078720;        // (8, 8192) as float
  float* losses = out + 34144256;        // [commitment, recon]

  float* A   = (float*)d_ws;             // 33554432 floats
  float* Bb  = A + 33554432;             // 33554432 floats
  float* t1  = Bb + 33554432;            // 65536
  float* cn  = t1 + 65536;               // 1024
  float* pc  = cn + 1024;                // 8192
  float* pr  = pc + 8192;                // 256

  // bf16 regions (reuse A/Bb halves):
  unsigned short* qb  = (unsigned short*)A;
  unsigned short* yb1 = (unsigned short*)Bb;
  unsigned short* yb2 = (unsigned short*)A;
  unsigned short* yb3 = (unsigned short*)(Bb + 16777216);
  unsigned short* yb4 = (unsigned short*)A;
  unsigned short* wsp   = (unsigned short*)(A + 16777216);
  unsigned short* zbuf  = wsp;
  unsigned short* wp1   = zbuf + 1024;
  unsigned short* wp2e  = wp1  + 1835008;
  unsigned short* wp2o  = wp2e + 917504;
  unsigned short* wp3e  = wp2o + 1048576;
  unsigned short* wp3o  = wp3e + 229376;
  unsigned short* wp4e  = wp3o + 262144;
  unsigned short* wp4o  = wp4e + 57344;

  dim3 blk(256);

  // ---- encoder (f32 scalar fmaf, LDS-staged x; BIT-EXACT) ----
  conv1d_k<15,1,7,1, 8><<<dim3(128,  4, 8), blk, 0, stream>>>(wave, e1w, e1b, A,   1,  64, 65536, 65536);
  conv1d_k<15,2,7,1, 8><<<dim3( 64,  8, 8), blk, 0, stream>>>(A,    e2w, e2b, Bb, 64, 128, 65536, 32768);
  conv1d_k<15,2,7,1, 8><<<dim3( 32, 16, 8), blk, 0, stream>>>(Bb,   e3w, e3b, A, 128, 256, 32768, 16384);
  conv1d_k<15,2,7,1, 8><<<dim3( 16, 32, 8), blk, 0, stream>>>(A,    e4w, e4b, Bb,256, 512, 16384,  8192);
  conv1d_k< 7,1,3,0,16><<<dim3( 16, 32, 8), blk, 0, stream>>>(Bb,   e5w, e5b, A, 512, 512,  8192,  8192);

  // ---- VQ (f32 numpy expression; BIT-EXACT) ----
  transpose_k<<<dim3(256, 16, 8), dim3(32, 8), 0, stream>>>(A, Bb, 512, 8192);
  rowsumsq_k<<<dim3(256), blk, 0, stream>>>(Bb, t1, 65536);
  rowsumsq_k<<<dim3(4),   blk, 0, stream>>>(cb, cn, 1024);
  vq_k<<<dim3(8192), blk, 0, stream>>>(Bb, cb, t1, cn, qout, codes, pc);

  // ---- decoder prep ----
  f32_to_bf16_k<<<dim3(32768), blk, 0, stream>>>(qout, qb, 8388608);
  zero_zbuf_k<<<dim3(4), blk, 0, stream>>>(zbuf);
  prepack_w_k<<<dim3(7168), blk, 0, stream>>>(d1w, wp1, 512, 512, 7, 7, 0, 1);
  prepack_w_k<<<dim3(3584), blk, 0, stream>>>(d2w, wp2e, 512, 256, 15, 7, 1, 2);
  prepack_w_k<<<dim3(4096), blk, 0, stream>>>(d2w, wp2o, 512, 256, 15, 8, 0, 2);
  prepack_w_k<<<dim3( 896), blk, 0, stream>>>(d3w, wp3e, 256, 128, 15, 7, 1, 2);
  prepack_w_k<<<dim3(1024), blk, 0, stream>>>(d3w, wp3o, 256, 128, 15, 8, 0, 2);
  prepack_w_k<<<dim3( 224), blk, 0, stream>>>(d4w, wp4e, 128,  64, 15, 7, 1, 2);
  prepack_w_k<<<dim3( 256), blk, 0, stream>>>(d4w, wp4o, 128,  64, 15, 8, 0, 2);

  // ---- decoder (bf16 MFMA implicit GEMM) ----
  mfma_convt_k<<<dim3(128, 32, 8), blk, 0, stream>>>(qb,  wp1,  d1b, yb1, zbuf, 512, 512, 8192, 8192, 1, 0, 7, 3);
  mfma_convt_k<<<dim3(128, 16, 8), blk, 0, stream>>>(yb1, wp2e, d2b, yb2, zbuf, 512, 256, 8192, 16384, 2, 0, 7, 3);
  mfma_convt_k<<<dim3(128, 16, 8), blk, 0, stream>>>(yb1, wp2o, d2b, yb2, zbuf, 512, 256, 8192, 16384, 2, 1, 8, 4);
  mfma_convt_k<<<dim3(256,  8, 8), blk, 0, stream>>>(yb2, wp3e, d3b, yb3, zbuf, 256, 128, 16384, 32768, 2, 0, 7, 3);
  mfma_convt_k<<<dim3(256,  8, 8), blk, 0, stream>>>(yb2, wp3o, d3b, yb3, zbuf, 256, 128, 16384, 32768, 2, 1, 8, 4);
  mfma_convt_k<<<dim3(512,  4, 8), blk, 0, stream>>>(yb3, wp4e, d4b, yb4, zbuf, 128,  64, 32768, 65536, 2, 0, 7, 3);
  mfma_convt_k<<<dim3(512,  4, 8), blk, 0, stream>>>(yb3, wp4o, d4b, yb4, zbuf, 128,  64, 32768, 65536, 2, 1, 8, 4);
  convt_final_bf16_k<<<dim3(256, 8), blk, 0, stream>>>(yb4, d5w, d5b, recon);

  // ---- losses ----
  absdiff_part_k<<<dim3(256), blk, 0, stream>>>(recon, wave, pr);
  finalize_k<<<dim3(1), blk, 0, stream>>>(pc, pr, losses);
}

// Round 12
// 24248.424 us; speedup vs baseline: 1.0476x; 1.0476x over previous
//
#include <hip/hip_runtime.h>
#include <hip/hip_bf16.h>
#include <math.h>

#define DEV __device__ __forceinline__

typedef __attribute__((ext_vector_type(8))) short s16x8;   // 8 bf16 in 4 VGPRs
typedef __attribute__((ext_vector_type(4))) float f32x4;

// ELU matching numpy (encoder only): f64 expm1 + single f32 round.
DEV float elu_f(float v) { return v > 0.0f ? v : (float)expm1((double)v); }
// fast f32 ELU (decoder epilogue; accuracy uncritical)
DEV float elu_fast(float v) { return v > 0.0f ? v : expm1f(v); }

DEV unsigned short f2bf(float f) {
  unsigned u = __float_as_uint(f);
  return (unsigned short)((u + 0x7fffu + ((u >> 16) & 1u)) >> 16);
}
DEV float bf2f(unsigned short s) { return __uint_as_float(((unsigned)s) << 16); }

// readfirstlane on float: value identical (wave-uniform already) -> SGPR home.
DEV float rfl(float v) {
  return __uint_as_float(__builtin_amdgcn_readfirstlane(__float_as_uint(v)));
}

// 4-float load with only 4B alignment guaranteed (weight rows are K-strided).
struct __attribute__((packed, aligned(4))) f4u { float x, y, z, w; };

#define QC(Q, C) ((C) == 0 ? (Q).x : (C) == 1 ? (Q).y : (C) == 2 ? (Q).z : (Q).w)

// ---------------------------------------------------------------------------
// Encoder conv1d K=15,S=2,PAD=7 (e2/e3/e4) — BIT-EXACT (ci outer, k inner
// sequential FMA chain, same order as all passing rounds). Changes vs R6:
//  * weights: per-wave uniform GLOBAL loads -> readfirstlane -> SGPR operands
//    (no weight LDS, no barriers, no wk VGPRs)
//  * x window phased: q0..q5 for k=0..7, then q6,q7 (reusing q0,q1 slots)
//    for k=8..14 -> <=24 live window VGPRs. Target: VGPR <= 64 tier (m69).
// block = 256 = 4 waves; wave -> 4 co (16 co/block); thread -> 8 outputs.
// ---------------------------------------------------------------------------
template<int ACT>
__global__ __launch_bounds__(256) void conv1d_s2_k(
    const float* __restrict__ x, const float* __restrict__ w,
    const float* __restrict__ bias, float* __restrict__ y,
    int Cin, int Cout, int Lin, int Lout)
{
  // M0 = 1: window float index for (g,k) is 1+2g+k in [1,29] -> q0..q7
  const int lane = threadIdx.x & 63;
  const int wv   = threadIdx.x >> 6;
  const int b    = blockIdx.z;
  const int cob  = blockIdx.y * 16;
  const int t0   = (blockIdx.x * 64 + lane) * 8;

  float acc[4][8];
  #pragma unroll
  for (int cc = 0; cc < 4; ++cc)
    #pragma unroll
    for (int g = 0; g < 8; ++g) acc[cc][g] = 0.0f;

  const float* xb   = x + (size_t)b * Cin * Lin;
  const int vbase  = t0 * 2 - 8;
  const bool fast  = (vbase >= 0) && (vbase + 32 <= Lin);

  const float* wr0 = w + (size_t)(cob + wv * 4 + 0) * Cin * 15;
  const float* wr1 = w + (size_t)(cob + wv * 4 + 1) * Cin * 15;
  const float* wr2 = w + (size_t)(cob + wv * 4 + 2) * Cin * 15;
  const float* wr3 = w + (size_t)(cob + wv * 4 + 3) * Cin * 15;

  float4 q0, q1, q2, q3, q4, q5, q6, q7;

#define XV2(I) ((I) < 4 ? QC(q0,(I)&3) : (I) < 8 ? QC(q1,(I)&3) : (I) < 12 ? QC(q2,(I)&3) : \
                (I) < 16 ? QC(q3,(I)&3) : (I) < 20 ? QC(q4,(I)&3) : (I) < 24 ? QC(q5,(I)&3) : \
                (I) < 28 ? QC(q6,(I)&3) : QC(q7,(I)&3))
#define LD4(Q, OFF)                                                           \
  if (fast) { Q = *(const float4*)(xpB + vbase + (OFF)); }                    \
  else {                                                                      \
    int i0_ = vbase + (OFF);                                                  \
    Q.x = (i0_ + 0 >= 0 && i0_ + 0 < Lin) ? xpB[i0_ + 0] : 0.0f;              \
    Q.y = (i0_ + 1 >= 0 && i0_ + 1 < Lin) ? xpB[i0_ + 1] : 0.0f;              \
    Q.z = (i0_ + 2 >= 0 && i0_ + 2 < Lin) ? xpB[i0_ + 2] : 0.0f;              \
    Q.w = (i0_ + 3 >= 0 && i0_ + 3 < Lin) ? xpB[i0_ + 3] : 0.0f;              \
  }

  #pragma unroll 1
  for (int ci = 0; ci < Cin; ++ci) {
    const float* xpB = xb + (size_t)ci * Lin;
    LD4(q0, 0)  LD4(q1, 4)  LD4(q2, 8)  LD4(q3, 12)  LD4(q4, 16)  LD4(q5, 20)

    // weights -> SGPRs (uniform rows; 4B-aligned dwordx4 reads, overlap trick)
    float wkf[4][15];
    #pragma unroll
    for (int cc = 0; cc < 4; ++cc) {
      const float* wr = (cc == 0 ? wr0 : cc == 1 ? wr1 : cc == 2 ? wr2 : wr3)
                        + (size_t)ci * 15;
      f4u a = *(const f4u*)(wr);
      f4u bq = *(const f4u*)(wr + 4);
      f4u c = *(const f4u*)(wr + 8);
      f4u d = *(const f4u*)(wr + 11);
      wkf[cc][0]=rfl(a.x);  wkf[cc][1]=rfl(a.y);  wkf[cc][2]=rfl(a.z);  wkf[cc][3]=rfl(a.w);
      wkf[cc][4]=rfl(bq.x); wkf[cc][5]=rfl(bq.y); wkf[cc][6]=rfl(bq.z); wkf[cc][7]=rfl(bq.w);
      wkf[cc][8]=rfl(c.x);  wkf[cc][9]=rfl(c.y);  wkf[cc][10]=rfl(c.z);
      wkf[cc][11]=rfl(d.x); wkf[cc][12]=rfl(d.y); wkf[cc][13]=rfl(d.z); wkf[cc][14]=rfl(d.w);
    }

    // phase A: k = 0..7 (window floats 1..22 in q0..q5)
    #pragma unroll
    for (int cc = 0; cc < 4; ++cc)
      #pragma unroll
      for (int k = 0; k < 8; ++k) {
        const float wv_ = wkf[cc][k];
        #pragma unroll
        for (int g = 0; g < 8; ++g)
          acc[cc][g] = fmaf(wv_, XV2(1 + 2 * g + k), acc[cc][g]);
      }

    LD4(q6, 24)  LD4(q7, 28)

    // phase B: k = 8..14 (window floats 9..29 in q2..q7; q0,q1 dead)
    #pragma unroll
    for (int cc = 0; cc < 4; ++cc)
      #pragma unroll
      for (int k = 8; k < 15; ++k) {
        const float wv_ = wkf[cc][k];
        #pragma unroll
        for (int g = 0; g < 8; ++g)
          acc[cc][g] = fmaf(wv_, XV2(1 + 2 * g + k), acc[cc][g]);
      }
  }
#undef XV2
#undef LD4

  #pragma unroll
  for (int cc = 0; cc < 4; ++cc) {
    const int co = cob + wv * 4 + cc;
    const float bv = bias[co];
    float res[8];
    #pragma unroll
    for (int g = 0; g < 8; ++g) {
      float v = acc[cc][g] + bv;
      if (ACT == 1) v = elu_f(v);
      res[g] = v;
    }
    float* yp = y + ((size_t)b * Cout + co) * Lout + t0;
    *(float4*)(yp)     = make_float4(res[0], res[1], res[2], res[3]);
    *(float4*)(yp + 4) = make_float4(res[4], res[5], res[6], res[7]);
  }
}

// ---------------------------------------------------------------------------
// Encoder conv1d S=1 (e1: K=15 PAD=7; e5: K=7 PAD=3) — same scheme, smaller
// window (M0=1; K15: floats 1..22 -> q0..q5; K7: floats 1..14 -> q0..q3).
// ---------------------------------------------------------------------------
template<int K, int PAD, int ACT>
__global__ __launch_bounds__(256) void conv1d_s1_k(
    const float* __restrict__ x, const float* __restrict__ w,
    const float* __restrict__ bias, float* __restrict__ y,
    int Cin, int Cout, int Lin, int Lout)
{
  constexpr int M0 = (4 - (PAD & 3)) & 3;      // 1 for PAD 7 or 3
  constexpr int W  = 7 + K;                    // PT=8, S=1
  constexpr int NQ = (M0 + W + 3) / 4;         // 6 (K15) / 4 (K7)

  const int lane = threadIdx.x & 63;
  const int wv   = threadIdx.x >> 6;
  const int b    = blockIdx.z;
  const int cob  = blockIdx.y * 16;
  const int t0   = (blockIdx.x * 64 + lane) * 8;

  float acc[4][8];
  #pragma unroll
  for (int cc = 0; cc < 4; ++cc)
    #pragma unroll
    for (int g = 0; g < 8; ++g) acc[cc][g] = 0.0f;

  const float* xb  = x + (size_t)b * Cin * Lin;
  const int vbase = t0 - PAD - M0;
  const bool fast = (vbase >= 0) && (vbase + 4 * NQ <= Lin);

  const float* wr0 = w + (size_t)(cob + wv * 4 + 0) * Cin * K;
  const float* wr1 = w + (size_t)(cob + wv * 4 + 1) * Cin * K;
  const float* wr2 = w + (size_t)(cob + wv * 4 + 2) * Cin * K;
  const float* wr3 = w + (size_t)(cob + wv * 4 + 3) * Cin * K;

  float4 q0, q1, q2, q3, q4, q5;

#define XV1(I) ((I) < 4 ? QC(q0,(I)&3) : (I) < 8 ? QC(q1,(I)&3) : (I) < 12 ? QC(q2,(I)&3) : \
                (I) < 16 ? QC(q3,(I)&3) : (I) < 20 ? QC(q4,(I)&3) : QC(q5,(I)&3))
#define LD4(Q, OFF)                                                           \
  if (fast) { Q = *(const float4*)(xpB + vbase + (OFF)); }                    \
  else {                                                                      \
    int i0_ = vbase + (OFF);                                                  \
    Q.x = (i0_ + 0 >= 0 && i0_ + 0 < Lin) ? xpB[i0_ + 0] : 0.0f;              \
    Q.y = (i0_ + 1 >= 0 && i0_ + 1 < Lin) ? xpB[i0_ + 1] : 0.0f;              \
    Q.z = (i0_ + 2 >= 0 && i0_ + 2 < Lin) ? xpB[i0_ + 2] : 0.0f;              \
    Q.w = (i0_ + 3 >= 0 && i0_ + 3 < Lin) ? xpB[i0_ + 3] : 0.0f;              \
  }

  #pragma unroll 1
  for (int ci = 0; ci < Cin; ++ci) {
    const float* xpB = xb + (size_t)ci * Lin;
    LD4(q0, 0)  LD4(q1, 4)  LD4(q2, 8)  LD4(q3, 12)
    if constexpr (NQ > 4) { LD4(q4, 16) LD4(q5, 20) }

    float wkf[4][K];
    #pragma unroll
    for (int cc = 0; cc < 4; ++cc) {
      const float* wr = (cc == 0 ? wr0 : cc == 1 ? wr1 : cc == 2 ? wr2 : wr3)
                        + (size_t)ci * K;
      if constexpr (K == 15) {
        f4u a = *(const f4u*)(wr);
        f4u bq = *(const f4u*)(wr + 4);
        f4u c = *(const f4u*)(wr + 8);
        f4u d = *(const f4u*)(wr + 11);
        wkf[cc][0]=rfl(a.x);  wkf[cc][1]=rfl(a.y);  wkf[cc][2]=rfl(a.z);  wkf[cc][3]=rfl(a.w);
        wkf[cc][4]=rfl(bq.x); wkf[cc][5]=rfl(bq.y); wkf[cc][6]=rfl(bq.z); wkf[cc][7]=rfl(bq.w);
        wkf[cc][8]=rfl(c.x);  wkf[cc][9]=rfl(c.y);  wkf[cc][10]=rfl(c.z);
        wkf[cc][11]=rfl(d.x); wkf[cc][12]=rfl(d.y); wkf[cc][13]=rfl(d.z); wkf[cc][14]=rfl(d.w);
      } else {  // K == 7
        f4u a = *(const f4u*)(wr);
        f4u bq = *(const f4u*)(wr + 3);
        wkf[cc][0]=rfl(a.x); wkf[cc][1]=rfl(a.y); wkf[cc][2]=rfl(a.z); wkf[cc][3]=rfl(a.w);
        wkf[cc][4]=rfl(bq.y); wkf[cc][5]=rfl(bq.z); wkf[cc][6]=rfl(bq.w);
      }
    }

    #pragma unroll
    for (int cc = 0; cc < 4; ++cc)
      #pragma unroll
      for (int k = 0; k < K; ++k) {
        const float wv_ = wkf[cc][k];
        #pragma unroll
        for (int g = 0; g < 8; ++g)
          acc[cc][g] = fmaf(wv_, XV1(M0 + g + k), acc[cc][g]);
      }
  }
#undef XV1
#undef LD4

  #pragma unroll
  for (int cc = 0; cc < 4; ++cc) {
    const int co = cob + wv * 4 + cc;
    const float bv = bias[co];
    float res[8];
    #pragma unroll
    for (int g = 0; g < 8; ++g) {
      float v = acc[cc][g] + bv;
      if (ACT == 1) v = elu_f(v);
      res[g] = v;
    }
    float* yp = y + ((size_t)b * Cout + co) * Lout + t0;
    *(float4*)(yp)     = make_float4(res[0], res[1], res[2], res[3]);
    *(float4*)(yp + 4) = make_float4(res[4], res[5], res[6], res[7]);
  }
}

// ---------------------------------------------------------------------------
// Batched 2D transpose: in (B, R, S) -> out (B, S, R).
// ---------------------------------------------------------------------------
__global__ __launch_bounds__(256) void transpose_k(
    const float* __restrict__ in, float* __restrict__ out, int R, int S_)
{
  __shared__ float tile[32][33];
  const int b  = blockIdx.z;
  const int r0 = blockIdx.y * 32;
  const int s0 = blockIdx.x * 32;
  const float* ib = in + (size_t)b * R * S_;
  float* ob = out + (size_t)b * R * S_;
  const int tx = threadIdx.x, ty = threadIdx.y;
  #pragma unroll
  for (int i = 0; i < 32; i += 8)
    tile[ty + i][tx] = ib[(size_t)(r0 + ty + i) * S_ + s0 + tx];
  __syncthreads();
  #pragma unroll
  for (int i = 0; i < 32; i += 8)
    ob[(size_t)(s0 + ty + i) * R + r0 + tx] = tile[tx][ty + i];
}

// ---------------------------------------------------------------------------
// numpy-pairwise-identical f32 sum of squares over 512 contiguous floats.
// ---------------------------------------------------------------------------
DEV float np_sumsq_128(const float* a) {
  float r[8];
  #pragma unroll
  for (int j = 0; j < 8; ++j) r[j] = __fmul_rn(a[j], a[j]);
  #pragma unroll
  for (int i = 8; i < 128; i += 8) {
    #pragma unroll
    for (int j = 0; j < 8; ++j)
      r[j] = __fadd_rn(r[j], __fmul_rn(a[i + j], a[i + j]));
  }
  float s01 = __fadd_rn(r[0], r[1]), s23 = __fadd_rn(r[2], r[3]);
  float s45 = __fadd_rn(r[4], r[5]), s67 = __fadd_rn(r[6], r[7]);
  return __fadd_rn(__fadd_rn(s01, s23), __fadd_rn(s45, s67));
}
DEV float np_sumsq_512(const float* a) {
  float s0 = np_sumsq_128(a);
  float s1 = np_sumsq_128(a + 128);
  float s2 = np_sumsq_128(a + 256);
  float s3 = np_sumsq_128(a + 384);
  return __fadd_rn(__fadd_rn(s0, s1), __fadd_rn(s2, s3));
}

__global__ __launch_bounds__(256) void rowsumsq_k(
    const float* __restrict__ in, float* __restrict__ out, int nrows)
{
  const int r = blockIdx.x * 256 + threadIdx.x;
  if (r >= nrows) return;
  out[r] = np_sumsq_512(in + (size_t)r * 512);
}

// ---------------------------------------------------------------------------
// VQ, numpy-f32-faithful (BIT-EXACT — do not change).
// ---------------------------------------------------------------------------
__global__ __launch_bounds__(256) void vq_k(
    const float* __restrict__ embT, const float* __restrict__ cb,
    const float* __restrict__ t1, const float* __restrict__ cnorm,
    float* __restrict__ qout, float* __restrict__ codes, float* __restrict__ pc)
{
  __shared__ __align__(16) float xs[8][512];
  __shared__ float rv[4][8];
  __shared__ int   ri[4][8];
  __shared__ int   bidx[8];
  __shared__ float cred[4];

  const int tid  = threadIdx.x;
  const int row0 = blockIdx.x * 8;

  for (int i = tid * 4; i < 4096; i += 1024)
    *(float4*)((float*)xs + i) = *(const float4*)(embT + (size_t)row0 * 512 + i);
  __syncthreads();

  float acc[4][8];
  #pragma unroll
  for (int j = 0; j < 4; ++j)
    #pragma unroll
    for (int r = 0; r < 8; ++r) acc[j][r] = 0.0f;

  const float* cbp = cb + (size_t)tid * 512;
  #pragma unroll 1
  for (int d0 = 0; d0 < 512; d0 += 4) {
    float4 xv[8];
    #pragma unroll
    for (int r = 0; r < 8; ++r) xv[r] = *(const float4*)&xs[r][d0];
    #pragma unroll
    for (int j = 0; j < 4; ++j) {
      float4 cv = *(const float4*)(cbp + (size_t)j * 256 * 512 + d0);
      #pragma unroll
      for (int r = 0; r < 8; ++r) {
        acc[j][r] = fmaf(cv.x, xv[r].x, acc[j][r]);
        acc[j][r] = fmaf(cv.y, xv[r].y, acc[j][r]);
        acc[j][r] = fmaf(cv.z, xv[r].z, acc[j][r]);
        acc[j][r] = fmaf(cv.w, xv[r].w, acc[j][r]);
      }
    }
  }

  float cnj[4];
  #pragma unroll
  for (int j = 0; j < 4; ++j) cnj[j] = cnorm[tid + 256 * j];
  float t1r[8];
  #pragma unroll
  for (int r = 0; r < 8; ++r) t1r[r] = t1[row0 + r];

  const int lane = tid & 63, wv = tid >> 6;
  #pragma unroll 1
  for (int r = 0; r < 8; ++r) {
    float bv = 0.0f; int bi = 0;
    #pragma unroll
    for (int j = 0; j < 4; ++j) {
      float dv = __fsub_rn(__fadd_rn(t1r[r], cnj[j]), __fmul_rn(2.0f, acc[j][r]));
      int ki = tid + 256 * j;
      if (j == 0 || dv < bv || (dv == bv && ki < bi)) { bv = dv; bi = ki; }
    }
    #pragma unroll
    for (int off = 32; off; off >>= 1) {
      float ov = __shfl_xor(bv, off);
      int   oi = __shfl_xor(bi, off);
      if (ov < bv || (ov == bv && oi < bi)) { bv = ov; bi = oi; }
    }
    if (lane == 0) { rv[wv][r] = bv; ri[wv][r] = bi; }
  }
  __syncthreads();
  if (tid < 8) {
    float bv = rv[0][tid]; int bi = ri[0][tid];
    #pragma unroll
    for (int wq = 1; wq < 4; ++wq) {
      float ov = rv[wq][tid]; int oi = ri[wq][tid];
      if (ov < bv || (ov == bv && oi < bi)) { bv = ov; bi = oi; }
    }
    bidx[tid] = bi;
    codes[row0 + tid] = (float)bi;
  }
  __syncthreads();

  float csum = 0.0f;
  for (int i = tid * 4; i < 4096; i += 1024) {
    int r = i >> 9, d = i & 511;
    float4 qv = *(const float4*)(cb + (size_t)bidx[r] * 512 + d);
    *(float4*)(qout + (size_t)(row0 + r) * 512 + d) = qv;
    float dx = qv.x - xs[r][d],     dy = qv.y - xs[r][d + 1];
    float dz = qv.z - xs[r][d + 2], dw = qv.w - xs[r][d + 3];
    csum += dx * dx + dy * dy + dz * dz + dw * dw;
  }
  #pragma unroll
  for (int off = 32; off; off >>= 1) csum += __shfl_xor(csum, off);
  if (lane == 0) cred[wv] = csum;
  __syncthreads();
  if (tid == 0) pc[blockIdx.x] = cred[0] + cred[1] + cred[2] + cred[3];
}

// ---------------------------------------------------------------------------
// f32 -> bf16 elementwise (4/thread)
// ---------------------------------------------------------------------------
__global__ __launch_bounds__(256) void f32_to_bf16_k(
    const float* __restrict__ in, unsigned short* __restrict__ out, int n4)
{
  int i = blockIdx.x * 256 + threadIdx.x;
  if (i >= n4) return;
  float4 v = *(const float4*)(in + (size_t)i * 4);
  ushort4 o;
  o.x = f2bf(v.x); o.y = f2bf(v.y); o.z = f2bf(v.z); o.w = f2bf(v.w);
  *(ushort4*)(out + (size_t)i * 4) = o;
}

__global__ __launch_bounds__(256) void zero_zbuf_k(unsigned short* z) {
  z[blockIdx.x * 256 + threadIdx.x] = 0;
}

// ---------------------------------------------------------------------------
// Decoder weight prepack: w [Cin][Cout][K] f32 -> wp bf16 (B-frag contiguous).
// ---------------------------------------------------------------------------
__global__ __launch_bounds__(256) void prepack_w_k(
    const float* __restrict__ w, unsigned short* __restrict__ wp,
    int Cin, int Cout, int K, int T, int m0, int ms)
{
  int id = blockIdx.x * 256 + threadIdx.x;
  int tot = T * Cin * Cout;
  if (id >= tot) return;
  int jj  = id / (Cin * Cout);
  int rem = id - jj * (Cin * Cout);
  int ci  = rem / Cout;
  int co  = rem - ci * Cout;
  int m   = m0 + ms * jj;
  float v = w[((size_t)ci * Cout + co) * K + m];
  size_t dst = ((size_t)((jj * (Cin >> 5) + (ci >> 5)) * 4 + ((ci & 31) >> 3))) * ((size_t)Cout * 8)
             + (size_t)co * 8 + (ci & 7);
  wp[dst] = f2bf(v);
}

// ---------------------------------------------------------------------------
// MFMA implicit-GEMM transposed-conv (one parity): bf16 in/out, f32 accum.
// ---------------------------------------------------------------------------
__global__ __launch_bounds__(256) void mfma_convt_k(
    const unsigned short* __restrict__ xb, const unsigned short* __restrict__ wp,
    const float* __restrict__ bias, unsigned short* __restrict__ yb,
    const unsigned short* __restrict__ zbuf,
    int Cin, int Cout, int Lin, int Lout, int S, int p, int T, int OFF0)
{
  const int lane = threadIdx.x & 63;
  const int wv   = threadIdx.x >> 6;
  const int r    = lane & 15;
  const int g    = lane >> 4;
  const int b    = blockIdx.z;
  const int u0   = blockIdx.x * 64 + wv * 16;
  const int co0  = blockIdx.y * 16;
  const int CB   = Cin >> 5;

  f32x4 acc = {0.f, 0.f, 0.f, 0.f};
  const unsigned short* xbb = xb + (size_t)b * Lin * Cin + g * 8;
  const unsigned short* zp  = zbuf + g * 8;
  const unsigned short* wpb = wp + (size_t)(co0 + r) * 8 + (size_t)g * Cout * 8;
  const size_t bstride = (size_t)4 * Cout * 8;

  const float bv = bias[co0 + r];

  #pragma unroll 1
  for (int jj = 0; jj < T; ++jj) {
    int u = u0 + r + OFF0 - jj;
    bool val = (u >= 0) && (u < Lin);
    const unsigned short* ap = val ? (xbb + (size_t)u * Cin) : zp;
    const unsigned short* bp = wpb + (size_t)jj * CB * bstride;
    #pragma unroll 2
    for (int cb = 0; cb < CB; ++cb) {
      s16x8 a  = *(const s16x8*)(ap + cb * 32);
      s16x8 bf = *(const s16x8*)(bp + (size_t)cb * bstride);
      acc = __builtin_amdgcn_mfma_f32_16x16x32_bf16(a, bf, acc, 0, 0, 0);
    }
  }

  #pragma unroll
  for (int reg = 0; reg < 4; ++reg) {
    int u  = u0 + g * 4 + reg;
    int o  = S * u + p;
    float v = elu_fast(acc[reg] + bv);
    yb[((size_t)b * Lout + o) * Cout + (co0 + r)] = f2bf(v);
  }
}

// ---------------------------------------------------------------------------
// Final decoder layer from bf16 row-major input [B][65536][64]: tanh conv.
// ---------------------------------------------------------------------------
__global__ __launch_bounds__(256) void convt_final_bf16_k(
    const unsigned short* __restrict__ xb, const float* __restrict__ w,
    const float* __restrict__ bias, float* __restrict__ y)
{
  __shared__ float wl[64][16];
  for (int i = threadIdx.x; i < 64 * 15; i += 256) wl[i / 15][i % 15] = w[i];
  __syncthreads();
  const int b = blockIdx.y;
  const int o = blockIdx.x * 256 + threadIdx.x;
  float acc = 0.0f;
  #pragma unroll 1
  for (int m = 0; m < 15; ++m) {
    int i = o + 7 - m;
    if (i < 0 || i >= 65536) continue;
    const unsigned short* xp = xb + ((size_t)b * 65536 + i) * 64;
    #pragma unroll
    for (int c8 = 0; c8 < 8; ++c8) {
      s16x8 xv = *(const s16x8*)(xp + c8 * 8);
      #pragma unroll
      for (int k = 0; k < 8; ++k)
        acc = fmaf(wl[c8 * 8 + k][m], bf2f((unsigned short)xv[k]), acc);
    }
  }
  y[(size_t)b * 65536 + o] = tanhf(acc + bias[0]);
}

// ---------------------------------------------------------------------------
// recon |diff| partial reduce + final losses
// ---------------------------------------------------------------------------
__global__ __launch_bounds__(256) void absdiff_part_k(
    const float* __restrict__ a, const float* __restrict__ b, float* __restrict__ pr)
{
  __shared__ float cred[4];
  const int tid  = threadIdx.x;
  const int base = blockIdx.x * 2048;
  float s = 0.0f;
  for (int i = tid * 4; i < 2048; i += 1024) {
    float4 x = *(const float4*)(a + base + i);
    float4 y = *(const float4*)(b + base + i);
    s += fabsf(x.x - y.x) + fabsf(x.y - y.y) + fabsf(x.z - y.z) + fabsf(x.w - y.w);
  }
  #pragma unroll
  for (int off = 32; off; off >>= 1) s += __shfl_xor(s, off);
  const int lane = tid & 63, wv = tid >> 6;
  if (lane == 0) cred[wv] = s;
  __syncthreads();
  if (tid == 0) pr[blockIdx.x] = cred[0] + cred[1] + cred[2] + cred[3];
}

__global__ __launch_bounds__(256) void finalize_k(
    const float* __restrict__ pc, const float* __restrict__ pr, float* __restrict__ outp)
{
  __shared__ float red[4];
  const int tid = threadIdx.x;
  const int lane = tid & 63, wv = tid >> 6;

  float s = 0.0f;
  for (int i = tid; i < 8192; i += 256) s += pc[i];
  #pragma unroll
  for (int off = 32; off; off >>= 1) s += __shfl_xor(s, off);
  if (lane == 0) red[wv] = s;
  __syncthreads();
  if (tid == 0) outp[0] = 0.25f * (red[0] + red[1] + red[2] + red[3]) / 33554432.0f;
  __syncthreads();

  float s2 = 0.0f;
  if (tid < 64) {
    for (int i = tid; i < 256; i += 64) s2 += pr[i];
    #pragma unroll
    for (int off = 32; off; off >>= 1) s2 += __shfl_xor(s2, off);
    if (tid == 0) outp[1] = s2 / 524288.0f;
  }
}

// ---------------------------------------------------------------------------
extern "C" void kernel_launch(void* const* d_in, const int* in_sizes, int n_in,
                              void* d_out, int out_size, void* d_ws, size_t ws_size,
                              hipStream_t stream) {
  const float* wave = (const float*)d_in[0];
  const float* e1w = (const float*)d_in[1];  const float* e1b = (const float*)d_in[2];
  const float* e2w = (const float*)d_in[3];  const float* e2b = (const float*)d_in[4];
  const float* e3w = (const float*)d_in[5];  const float* e3b = (const float*)d_in[6];
  const float* e4w = (const float*)d_in[7];  const float* e4b = (const float*)d_in[8];
  const float* e5w = (const float*)d_in[9];  const float* e5b = (const float*)d_in[10];
  const float* cb  = (const float*)d_in[11];
  const float* d1w = (const float*)d_in[12]; const float* d1b = (const float*)d_in[13];
  const float* d2w = (const float*)d_in[14]; const float* d2b = (const float*)d_in[15];
  const float* d3w = (const float*)d_in[16]; const float* d3b = (const float*)d_in[17];
  const float* d4w = (const float*)d_in[18]; const float* d4b = (const float*)d_in[19];
  const float* d5w = (const float*)d_in[20]; const float* d5b = (const float*)d_in[21];

  float* out = (float*)d_out;
  float* recon  = out;                   // (8, 65536)
  float* qout   = out + 524288;          // (8, 8192, 512)
  float* codes  = out + 34078720;        // (8, 8192) as float
  float* losses = out + 34144256;        // [commitment, recon]

  float* A   = (float*)d_ws;             // 33554432 floats
  float* Bb  = A + 33554432;             // 33554432 floats
  float* t1  = Bb + 33554432;            // 65536
  float* cn  = t1 + 65536;               // 1024
  float* pc  = cn + 1024;                // 8192
  float* pr  = pc + 8192;                // 256

  // bf16 regions (reuse A/Bb halves):
  unsigned short* qb  = (unsigned short*)A;
  unsigned short* yb1 = (unsigned short*)Bb;
  unsigned short* yb2 = (unsigned short*)A;
  unsigned short* yb3 = (unsigned short*)(Bb + 16777216);
  unsigned short* yb4 = (unsigned short*)A;
  unsigned short* wsp   = (unsigned short*)(A + 16777216);
  unsigned short* zbuf  = wsp;
  unsigned short* wp1   = zbuf + 1024;
  unsigned short* wp2e  = wp1  + 1835008;
  unsigned short* wp2o  = wp2e + 917504;
  unsigned short* wp3e  = wp2o + 1048576;
  unsigned short* wp3o  = wp3e + 229376;
  unsigned short* wp4e  = wp3o + 262144;
  unsigned short* wp4o  = wp4e + 57344;

  dim3 blk(256);

  // ---- encoder (f32 scalar fmaf, SGPR weights, no LDS/barriers; BIT-EXACT) ----
  conv1d_s1_k<15,7,1><<<dim3(128,  4, 8), blk, 0, stream>>>(wave, e1w, e1b, A,   1,  64, 65536, 65536);
  conv1d_s2_k<1>     <<<dim3( 64,  8, 8), blk, 0, stream>>>(A,    e2w, e2b, Bb, 64, 128, 65536, 32768);
  conv1d_s2_k<1>     <<<dim3( 32, 16, 8), blk, 0, stream>>>(Bb,   e3w, e3b, A, 128, 256, 32768, 16384);
  conv1d_s2_k<1>     <<<dim3( 16, 32, 8), blk, 0, stream>>>(A,    e4w, e4b, Bb,256, 512, 16384,  8192);
  conv1d_s1_k< 7,3,0><<<dim3( 16, 32, 8), blk, 0, stream>>>(Bb,   e5w, e5b, A, 512, 512,  8192,  8192);

  // ---- VQ (f32 numpy expression; BIT-EXACT) ----
  transpose_k<<<dim3(256, 16, 8), dim3(32, 8), 0, stream>>>(A, Bb, 512, 8192);
  rowsumsq_k<<<dim3(256), blk, 0, stream>>>(Bb, t1, 65536);
  rowsumsq_k<<<dim3(4),   blk, 0, stream>>>(cb, cn, 1024);
  vq_k<<<dim3(8192), blk, 0, stream>>>(Bb, cb, t1, cn, qout, codes, pc);

  // ---- decoder prep ----
  f32_to_bf16_k<<<dim3(32768), blk, 0, stream>>>(qout, qb, 8388608);
  zero_zbuf_k<<<dim3(4), blk, 0, stream>>>(zbuf);
  prepack_w_k<<<dim3(7168), blk, 0, stream>>>(d1w, wp1, 512, 512, 7, 7, 0, 1);
  prepack_w_k<<<dim3(3584), blk, 0, stream>>>(d2w, wp2e, 512, 256, 15, 7, 1, 2);
  prepack_w_k<<<dim3(4096), blk, 0, stream>>>(d2w, wp2o, 512, 256, 15, 8, 0, 2);
  prepack_w_k<<<dim3( 896), blk, 0, stream>>>(d3w, wp3e, 256, 128, 15, 7, 1, 2);
  prepack_w_k<<<dim3(1024), blk, 0, stream>>>(d3w, wp3o, 256, 128, 15, 8, 0, 2);
  prepack_w_k<<<dim3( 224), blk, 0, stream>>>(d4w, wp4e, 128,  64, 15, 7, 1, 2);
  prepack_w_k<<<dim3( 256), blk, 0, stream>>>(d4w, wp4o, 128,  64, 15, 8, 0, 2);

  // ---- decoder (bf16 MFMA implicit GEMM) ----
  mfma_convt_k<<<dim3(128, 32, 8), blk, 0, stream>>>(qb,  wp1,  d1b, yb1, zbuf, 512, 512, 8192, 8192, 1, 0, 7, 3);
  mfma_convt_k<<<dim3(128, 16, 8), blk, 0, stream>>>(yb1, wp2e, d2b, yb2, zbuf, 512, 256, 8192, 16384, 2, 0, 7, 3);
  mfma_convt_k<<<dim3(128, 16, 8), blk, 0, stream>>>(yb1, wp2o, d2b, yb2, zbuf, 512, 256, 8192, 16384, 2, 1, 8, 4);
  mfma_convt_k<<<dim3(256,  8, 8), blk, 0, stream>>>(yb2, wp3e, d3b, yb3, zbuf, 256, 128, 16384, 32768, 2, 0, 7, 3);
  mfma_convt_k<<<dim3(256,  8, 8), blk, 0, stream>>>(yb2, wp3o, d3b, yb3, zbuf, 256, 128, 16384, 32768, 2, 1, 8, 4);
  mfma_convt_k<<<dim3(512,  4, 8), blk, 0, stream>>>(yb3, wp4e, d4b, yb4, zbuf, 128,  64, 32768, 65536, 2, 0, 7, 3);
  mfma_convt_k<<<dim3(512,  4, 8), blk, 0, stream>>>(yb3, wp4o, d4b, yb4, zbuf, 128,  64, 32768, 65536, 2, 1, 8, 4);
  convt_final_bf16_k<<<dim3(256, 8), blk, 0, stream>>>(yb4, d5w, d5b, recon);

  // ---- losses ----
  absdiff_part_k<<<dim3(256), blk, 0, stream>>>(recon, wave, pr);
  finalize_k<<<dim3(1), blk, 0, stream>>>(pc, pr, losses);
}

// Round 14
// 20990.942 us; speedup vs baseline: 1.2101x; 1.1552x over previous
//
#include <hip/hip_runtime.h>
#include <hip/hip_bf16.h>
#include <math.h>

#define DEV __device__ __forceinline__

typedef __attribute__((ext_vector_type(8))) short s16x8;   // 8 bf16 in 4 VGPRs
typedef __attribute__((ext_vector_type(4))) float f32x4;

// ELU matching numpy (encoder only): f64 expm1 + single f32 round.
DEV float elu_f(float v) { return v > 0.0f ? v : (float)expm1((double)v); }
// fast f32 ELU (decoder epilogue; accuracy uncritical)
DEV float elu_fast(float v) { return v > 0.0f ? v : expm1f(v); }

DEV unsigned short f2bf(float f) {
  unsigned u = __float_as_uint(f);
  return (unsigned short)((u + 0x7fffu + ((u >> 16) & 1u)) >> 16);
}
DEV float bf2f(unsigned short s) { return __uint_as_float(((unsigned)s) << 16); }

#define QC(Q, C) ((C) == 0 ? (Q).x : (C) == 1 ? (Q).y : (C) == 2 ? (Q).z : (Q).w)

// ---------------------------------------------------------------------------
// f32 forward conv1d (encoder — BIT-EXACT: per output the FMA chain is
// sequential (ci outer, k inner), identical to rounds 4-12 passing kernels).
// R6 structure (LDS-staged weights, barriers per 16-ci chunk, 4 co/wave,
// 8 outputs/thread) + PHASED WINDOW for K15/S2: k=0..7 uses q0..q5, then
// q6,q7 loaded, k=8..14 uses q2..q7 -> <=24 live window VGPRs (was 30).
// Goal: VGPR <= 64 occupancy tier (m69) with R6's proven instruction mix.
// ---------------------------------------------------------------------------
template<int K, int S, int PAD, int ACT>
__global__ __launch_bounds__(256) void conv1d_k(
    const float* __restrict__ x, const float* __restrict__ w,
    const float* __restrict__ bias, float* __restrict__ y,
    int Cin, int Cout, int Lin, int Lout)
{
  constexpr int PT = 8;
  constexpr int W  = (PT - 1) * S + K;
  constexpr int M0 = (4 - (PAD & 3)) & 3;      // 1 for PAD 7/3
  constexpr int NQ = (M0 + W + 3) / 4;         // S2K15: 8, S1K15: 6, S1K7: 4
  constexpr int CC = 16;
  constexpr int KP = (K + 3) & ~3;
  constexpr bool PHASED = (S == 2 && K == 15);

  const int lane = threadIdx.x & 63;
  const int wv   = threadIdx.x >> 6;
  const int b    = blockIdx.z;
  const int cob  = blockIdx.y * 16;
  const int t0   = (blockIdx.x * 64 + lane) * PT;

  __shared__ __align__(16) float wl[16][CC][KP];

  float acc[4][PT];
  #pragma unroll
  for (int cc = 0; cc < 4; ++cc)
    #pragma unroll
    for (int g = 0; g < PT; ++g) acc[cc][g] = 0.0f;

  const float* xb  = x + (size_t)b * Cin * Lin;
  const int vbase = t0 * S - PAD - M0;
  const bool fast = (vbase >= 0) && (vbase + 4 * NQ <= Lin);

  float4 q0, q1, q2, q3, q4, q5, q6, q7;

#define XV(I) ((I) < 4 ? QC(q0,(I)&3) : (I) < 8 ? QC(q1,(I)&3) : (I) < 12 ? QC(q2,(I)&3) : \
               (I) < 16 ? QC(q3,(I)&3) : (I) < 20 ? QC(q4,(I)&3) : (I) < 24 ? QC(q5,(I)&3) : \
               (I) < 28 ? QC(q6,(I)&3) : QC(q7,(I)&3))
#define LD4(Q, OFF)                                                           \
  if (fast) { Q = *(const float4*)(xpB + vbase + (OFF)); }                    \
  else {                                                                      \
    int i0_ = vbase + (OFF);                                                  \
    Q.x = (i0_ + 0 >= 0 && i0_ + 0 < Lin) ? xpB[i0_ + 0] : 0.0f;              \
    Q.y = (i0_ + 1 >= 0 && i0_ + 1 < Lin) ? xpB[i0_ + 1] : 0.0f;              \
    Q.z = (i0_ + 2 >= 0 && i0_ + 2 < Lin) ? xpB[i0_ + 2] : 0.0f;              \
    Q.w = (i0_ + 3 >= 0 && i0_ + 3 < Lin) ? xpB[i0_ + 3] : 0.0f;              \
  }

  for (int c0 = 0; c0 < Cin; c0 += CC) {
    const int cn = (Cin - c0 < CC) ? (Cin - c0) : CC;
    __syncthreads();
    for (int i = threadIdx.x; i < 16 * cn * K; i += 256) {
      int cc  = i / (cn * K);
      int rem = i - cc * (cn * K);
      int ci  = rem / K;
      int k   = rem - ci * K;
      wl[cc][ci][k] = w[((size_t)(cob + cc) * Cin + (c0 + ci)) * K + k];
    }
    __syncthreads();
    #pragma unroll 1
    for (int ci = 0; ci < cn; ++ci) {
      const float* xpB = xb + (size_t)(c0 + ci) * Lin;
      if constexpr (PHASED) {
        LD4(q0, 0) LD4(q1, 4) LD4(q2, 8) LD4(q3, 12) LD4(q4, 16) LD4(q5, 20)
        // phase A: k = 0..7 (window floats 1..22 -> q0..q5)
        #pragma unroll
        for (int cc = 0; cc < 4; ++cc) {
          float wk[8];
          { float4 t = *(const float4*)&wl[wv*4+cc][ci][0];
            wk[0]=t.x; wk[1]=t.y; wk[2]=t.z; wk[3]=t.w; }
          { float4 t = *(const float4*)&wl[wv*4+cc][ci][4];
            wk[4]=t.x; wk[5]=t.y; wk[6]=t.z; wk[7]=t.w; }
          #pragma unroll
          for (int k = 0; k < 8; ++k) {
            #pragma unroll
            for (int g = 0; g < 8; ++g)
              acc[cc][g] = fmaf(wk[k], XV(1 + 2*g + k), acc[cc][g]);
          }
        }
        LD4(q6, 24) LD4(q7, 28)
        // phase B: k = 8..14 (window floats 9..29 -> q2..q7; q0,q1 dead)
        #pragma unroll
        for (int cc = 0; cc < 4; ++cc) {
          float wk[7];
          { float4 t = *(const float4*)&wl[wv*4+cc][ci][8];
            wk[0]=t.x; wk[1]=t.y; wk[2]=t.z; wk[3]=t.w; }
          { float4 t = *(const float4*)&wl[wv*4+cc][ci][12];
            wk[4]=t.x; wk[5]=t.y; wk[6]=t.z; }
          #pragma unroll
          for (int k = 8; k < 15; ++k) {
            #pragma unroll
            for (int g = 0; g < 8; ++g)
              acc[cc][g] = fmaf(wk[k-8], XV(1 + 2*g + k), acc[cc][g]);
          }
        }
      } else {
        LD4(q0, 0) LD4(q1, 4) LD4(q2, 8) LD4(q3, 12)
        if constexpr (NQ > 4) { LD4(q4, 16) LD4(q5, 20) }
        #pragma unroll
        for (int cc = 0; cc < 4; ++cc) {
          float wk[KP];
          const float4* wq4 = (const float4*)(&wl[wv*4+cc][ci][0]);
          #pragma unroll
          for (int q4i = 0; q4i < KP/4; ++q4i) {
            float4 t = wq4[q4i];
            wk[4*q4i+0]=t.x; wk[4*q4i+1]=t.y; wk[4*q4i+2]=t.z; wk[4*q4i+3]=t.w;
          }
          #pragma unroll
          for (int k = 0; k < K; ++k) {
            #pragma unroll
            for (int g = 0; g < 8; ++g)
              acc[cc][g] = fmaf(wk[k], XV(M0 + g*S + k), acc[cc][g]);
          }
        }
      }
    }
  }
#undef XV
#undef LD4

  #pragma unroll
  for (int cc = 0; cc < 4; ++cc) {
    const int co = cob + wv * 4 + cc;
    const float bv = bias[co];
    float res[PT];
    #pragma unroll
    for (int g = 0; g < PT; ++g) {
      float v = acc[cc][g] + bv;
      if (ACT == 1) v = elu_f(v);
      res[g] = v;
    }
    float* yp = y + ((size_t)b * Cout + co) * Lout + t0;
    *(float4*)(yp)     = make_float4(res[0], res[1], res[2], res[3]);
    *(float4*)(yp + 4) = make_float4(res[4], res[5], res[6], res[7]);
  }
}

// ---------------------------------------------------------------------------
// Batched 2D transpose: in (B, R, S) -> out (B, S, R).
// ---------------------------------------------------------------------------
__global__ __launch_bounds__(256) void transpose_k(
    const float* __restrict__ in, float* __restrict__ out, int R, int S_)
{
  __shared__ float tile[32][33];
  const int b  = blockIdx.z;
  const int r0 = blockIdx.y * 32;
  const int s0 = blockIdx.x * 32;
  const float* ib = in + (size_t)b * R * S_;
  float* ob = out + (size_t)b * R * S_;
  const int tx = threadIdx.x, ty = threadIdx.y;
  #pragma unroll
  for (int i = 0; i < 32; i += 8)
    tile[ty + i][tx] = ib[(size_t)(r0 + ty + i) * S_ + s0 + tx];
  __syncthreads();
  #pragma unroll
  for (int i = 0; i < 32; i += 8)
    ob[(size_t)(s0 + ty + i) * R + r0 + tx] = tile[tx][ty + i];
}

// ---------------------------------------------------------------------------
// numpy-pairwise-identical f32 sum of squares over 512 contiguous floats.
// ---------------------------------------------------------------------------
DEV float np_sumsq_128(const float* a) {
  float r[8];
  #pragma unroll
  for (int j = 0; j < 8; ++j) r[j] = __fmul_rn(a[j], a[j]);
  #pragma unroll
  for (int i = 8; i < 128; i += 8) {
    #pragma unroll
    for (int j = 0; j < 8; ++j)
      r[j] = __fadd_rn(r[j], __fmul_rn(a[i + j], a[i + j]));
  }
  float s01 = __fadd_rn(r[0], r[1]), s23 = __fadd_rn(r[2], r[3]);
  float s45 = __fadd_rn(r[4], r[5]), s67 = __fadd_rn(r[6], r[7]);
  return __fadd_rn(__fadd_rn(s01, s23), __fadd_rn(s45, s67));
}
DEV float np_sumsq_512(const float* a) {
  float s0 = np_sumsq_128(a);
  float s1 = np_sumsq_128(a + 128);
  float s2 = np_sumsq_128(a + 256);
  float s3 = np_sumsq_128(a + 384);
  return __fadd_rn(__fadd_rn(s0, s1), __fadd_rn(s2, s3));
}

__global__ __launch_bounds__(256) void rowsumsq_k(
    const float* __restrict__ in, float* __restrict__ out, int nrows)
{
  const int r = blockIdx.x * 256 + threadIdx.x;
  if (r >= nrows) return;
  out[r] = np_sumsq_512(in + (size_t)r * 512);
}

// ---------------------------------------------------------------------------
// VQ, numpy-f32-faithful (BIT-EXACT — do not change the dist/argmin path).
// Round-13 addition: also emits q as bf16 (qb) for the decoder, fusing the
// former f32_to_bf16 pass into the gather loop.
// ---------------------------------------------------------------------------
__global__ __launch_bounds__(256) void vq_k(
    const float* __restrict__ embT, const float* __restrict__ cb,
    const float* __restrict__ t1, const float* __restrict__ cnorm,
    float* __restrict__ qout, unsigned short* __restrict__ qb,
    float* __restrict__ codes, float* __restrict__ pc)
{
  __shared__ __align__(16) float xs[8][512];
  __shared__ float rv[4][8];
  __shared__ int   ri[4][8];
  __shared__ int   bidx[8];
  __shared__ float cred[4];

  const int tid  = threadIdx.x;
  const int row0 = blockIdx.x * 8;

  for (int i = tid * 4; i < 4096; i += 1024)
    *(float4*)((float*)xs + i) = *(const float4*)(embT + (size_t)row0 * 512 + i);
  __syncthreads();

  float acc[4][8];
  #pragma unroll
  for (int j = 0; j < 4; ++j)
    #pragma unroll
    for (int r = 0; r < 8; ++r) acc[j][r] = 0.0f;

  const float* cbp = cb + (size_t)tid * 512;
  #pragma unroll 1
  for (int d0 = 0; d0 < 512; d0 += 4) {
    float4 xv[8];
    #pragma unroll
    for (int r = 0; r < 8; ++r) xv[r] = *(const float4*)&xs[r][d0];
    #pragma unroll
    for (int j = 0; j < 4; ++j) {
      float4 cv = *(const float4*)(cbp + (size_t)j * 256 * 512 + d0);
      #pragma unroll
      for (int r = 0; r < 8; ++r) {
        acc[j][r] = fmaf(cv.x, xv[r].x, acc[j][r]);
        acc[j][r] = fmaf(cv.y, xv[r].y, acc[j][r]);
        acc[j][r] = fmaf(cv.z, xv[r].z, acc[j][r]);
        acc[j][r] = fmaf(cv.w, xv[r].w, acc[j][r]);
      }
    }
  }

  float cnj[4];
  #pragma unroll
  for (int j = 0; j < 4; ++j) cnj[j] = cnorm[tid + 256 * j];
  float t1r[8];
  #pragma unroll
  for (int r = 0; r < 8; ++r) t1r[r] = t1[row0 + r];

  const int lane = tid & 63, wv = tid >> 6;
  #pragma unroll 1
  for (int r = 0; r < 8; ++r) {
    float bv = 0.0f; int bi = 0;
    #pragma unroll
    for (int j = 0; j < 4; ++j) {
      float dv = __fsub_rn(__fadd_rn(t1r[r], cnj[j]), __fmul_rn(2.0f, acc[j][r]));
      int ki = tid + 256 * j;
      if (j == 0 || dv < bv || (dv == bv && ki < bi)) { bv = dv; bi = ki; }
    }
    #pragma unroll
    for (int off = 32; off; off >>= 1) {
      float ov = __shfl_xor(bv, off);
      int   oi = __shfl_xor(bi, off);
      if (ov < bv || (ov == bv && oi < bi)) { bv = ov; bi = oi; }
    }
    if (lane == 0) { rv[wv][r] = bv; ri[wv][r] = bi; }
  }
  __syncthreads();
  if (tid < 8) {
    float bv = rv[0][tid]; int bi = ri[0][tid];
    #pragma unroll
    for (int wq = 1; wq < 4; ++wq) {
      float ov = rv[wq][tid]; int oi = ri[wq][tid];
      if (ov < bv || (ov == bv && oi < bi)) { bv = ov; bi = oi; }
    }
    bidx[tid] = bi;
    codes[row0 + tid] = (float)bi;
  }
  __syncthreads();

  float csum = 0.0f;
  for (int i = tid * 4; i < 4096; i += 1024) {
    int r = i >> 9, d = i & 511;
    float4 qv = *(const float4*)(cb + (size_t)bidx[r] * 512 + d);
    *(float4*)(qout + (size_t)(row0 + r) * 512 + d) = qv;
    ushort4 ob;
    ob.x = f2bf(qv.x); ob.y = f2bf(qv.y); ob.z = f2bf(qv.z); ob.w = f2bf(qv.w);
    *(ushort4*)(qb + (size_t)(row0 + r) * 512 + d) = ob;
    float dx = qv.x - xs[r][d],     dy = qv.y - xs[r][d + 1];
    float dz = qv.z - xs[r][d + 2], dw = qv.w - xs[r][d + 3];
    csum += dx * dx + dy * dy + dz * dz + dw * dw;
  }
  #pragma unroll
  for (int off = 32; off; off >>= 1) csum += __shfl_xor(csum, off);
  if (lane == 0) cred[wv] = csum;
  __syncthreads();
  if (tid == 0) pc[blockIdx.x] = cred[0] + cred[1] + cred[2] + cred[3];
}

__global__ __launch_bounds__(256) void zero_zbuf_k(unsigned short* z) {
  z[blockIdx.x * 256 + threadIdx.x] = 0;
}

// ---------------------------------------------------------------------------
// Decoder weight prepack: w [Cin][Cout][K] f32 -> wp bf16 (B-frag contiguous).
// ---------------------------------------------------------------------------
__global__ __launch_bounds__(256) void prepack_w_k(
    const float* __restrict__ w, unsigned short* __restrict__ wp,
    int Cin, int Cout, int K, int T, int m0, int ms)
{
  int id = blockIdx.x * 256 + threadIdx.x;
  int tot = T * Cin * Cout;
  if (id >= tot) return;
  int jj  = id / (Cin * Cout);
  int rem = id - jj * (Cin * Cout);
  int ci  = rem / Cout;
  int co  = rem - ci * Cout;
  int m   = m0 + ms * jj;
  float v = w[((size_t)ci * Cout + co) * K + m];
  size_t dst = ((size_t)((jj * (Cin >> 5) + (ci >> 5)) * 4 + ((ci & 31) >> 3))) * ((size_t)Cout * 8)
             + (size_t)co * 8 + (ci & 7);
  wp[dst] = f2bf(v);
}

// ---------------------------------------------------------------------------
// MFMA implicit-GEMM transposed-conv (one parity): bf16 in/out, f32 accum.
// ---------------------------------------------------------------------------
__global__ __launch_bounds__(256) void mfma_convt_k(
    const unsigned short* __restrict__ xb, const unsigned short* __restrict__ wp,
    const float* __restrict__ bias, unsigned short* __restrict__ yb,
    const unsigned short* __restrict__ zbuf,
    int Cin, int Cout, int Lin, int Lout, int S, int p, int T, int OFF0)
{
  const int lane = threadIdx.x & 63;
  const int wv   = threadIdx.x >> 6;
  const int r    = lane & 15;
  const int g    = lane >> 4;
  const int b    = blockIdx.z;
  const int u0   = blockIdx.x * 64 + wv * 16;
  const int co0  = blockIdx.y * 16;
  const int CB   = Cin >> 5;

  f32x4 acc = {0.f, 0.f, 0.f, 0.f};
  const unsigned short* xbb = xb + (size_t)b * Lin * Cin + g * 8;
  const unsigned short* zp  = zbuf + g * 8;
  const unsigned short* wpb = wp + (size_t)(co0 + r) * 8 + (size_t)g * Cout * 8;
  const size_t bstride = (size_t)4 * Cout * 8;

  const float bv = bias[co0 + r];

  #pragma unroll 1
  for (int jj = 0; jj < T; ++jj) {
    int u = u0 + r + OFF0 - jj;
    bool val = (u >= 0) && (u < Lin);
    const unsigned short* ap = val ? (xbb + (size_t)u * Cin) : zp;
    const unsigned short* bp = wpb + (size_t)jj * CB * bstride;
    #pragma unroll 2
    for (int cb = 0; cb < CB; ++cb) {
      s16x8 a  = *(const s16x8*)(ap + cb * 32);
      s16x8 bf = *(const s16x8*)(bp + (size_t)cb * bstride);
      acc = __builtin_amdgcn_mfma_f32_16x16x32_bf16(a, bf, acc, 0, 0, 0);
    }
  }

  #pragma unroll
  for (int reg = 0; reg < 4; ++reg) {
    int u  = u0 + g * 4 + reg;
    int o  = S * u + p;
    float v = elu_fast(acc[reg] + bv);
    yb[((size_t)b * Lout + o) * Cout + (co0 + r)] = f2bf(v);
  }
}

// ---------------------------------------------------------------------------
// Final decoder layer from bf16 row-major input [B][65536][64]: tanh conv.
// ---------------------------------------------------------------------------
__global__ __launch_bounds__(256) void convt_final_bf16_k(
    const unsigned short* __restrict__ xb, const float* __restrict__ w,
    const float* __restrict__ bias, float* __restrict__ y)
{
  __shared__ float wl[64][16];
  for (int i = threadIdx.x; i < 64 * 15; i += 256) wl[i / 15][i % 15] = w[i];
  __syncthreads();
  const int b = blockIdx.y;
  const int o = blockIdx.x * 256 + threadIdx.x;
  float acc = 0.0f;
  #pragma unroll 1
  for (int m = 0; m < 15; ++m) {
    int i = o + 7 - m;
    if (i < 0 || i >= 65536) continue;
    const unsigned short* xp = xb + ((size_t)b * 65536 + i) * 64;
    #pragma unroll
    for (int c8 = 0; c8 < 8; ++c8) {
      s16x8 xv = *(const s16x8*)(xp + c8 * 8);
      #pragma unroll
      for (int k = 0; k < 8; ++k)
        acc = fmaf(wl[c8 * 8 + k][m], bf2f((unsigned short)xv[k]), acc);
    }
  }
  y[(size_t)b * 65536 + o] = tanhf(acc + bias[0]);
}

// ---------------------------------------------------------------------------
// recon |diff| partial reduce + final losses
// ---------------------------------------------------------------------------
__global__ __launch_bounds__(256) void absdiff_part_k(
    const float* __restrict__ a, const float* __restrict__ b, float* __restrict__ pr)
{
  __shared__ float cred[4];
  const int tid  = threadIdx.x;
  const int base = blockIdx.x * 2048;
  float s = 0.0f;
  for (int i = tid * 4; i < 2048; i += 1024) {
    float4 x = *(const float4*)(a + base + i);
    float4 y = *(const float4*)(b + base + i);
    s += fabsf(x.x - y.x) + fabsf(x.y - y.y) + fabsf(x.z - y.z) + fabsf(x.w - y.w);
  }
  #pragma unroll
  for (int off = 32; off; off >>= 1) s += __shfl_xor(s, off);
  const int lane = tid & 63, wv = tid >> 6;
  if (lane == 0) cred[wv] = s;
  __syncthreads();
  if (tid == 0) pr[blockIdx.x] = cred[0] + cred[1] + cred[2] + cred[3];
}

__global__ __launch_bounds__(256) void finalize_k(
    const float* __restrict__ pc, const float* __restrict__ pr, float* __restrict__ outp)
{
  __shared__ float red[4];
  const int tid = threadIdx.x;
  const int lane = tid & 63, wv = tid >> 6;

  float s = 0.0f;
  for (int i = tid; i < 8192; i += 256) s += pc[i];
  #pragma unroll
  for (int off = 32; off; off >>= 1) s += __shfl_xor(s, off);
  if (lane == 0) red[wv] = s;
  __syncthreads();
  if (tid == 0) outp[0] = 0.25f * (red[0] + red[1] + red[2] + red[3]) / 33554432.0f;
  __syncthreads();

  float s2 = 0.0f;
  if (tid < 64) {
    for (int i = tid; i < 256; i += 64) s2 += pr[i];
    #pragma unroll
    for (int off = 32; off; off >>= 1) s2 += __shfl_xor(s2, off);
    if (tid == 0) outp[1] = s2 / 524288.0f;
  }
}

// ---------------------------------------------------------------------------
extern "C" void kernel_launch(void* const* d_in, const int* in_sizes, int n_in,
                              void* d_out, int out_size, void* d_ws, size_t ws_size,
                              hipStream_t stream) {
  const float* wave = (const float*)d_in[0];
  const float* e1w = (const float*)d_in[1];  const float* e1b = (const float*)d_in[2];
  const float* e2w = (const float*)d_in[3];  const float* e2b = (const float*)d_in[4];
  const float* e3w = (const float*)d_in[5];  const float* e3b = (const float*)d_in[6];
  const float* e4w = (const float*)d_in[7];  const float* e4b = (const float*)d_in[8];
  const float* e5w = (const float*)d_in[9];  const float* e5b = (const float*)d_in[10];
  const float* cb  = (const float*)d_in[11];
  const float* d1w = (const float*)d_in[12]; const float* d1b = (const float*)d_in[13];
  const float* d2w = (const float*)d_in[14]; const float* d2b = (const float*)d_in[15];
  const float* d3w = (const float*)d_in[16]; const float* d3b = (const float*)d_in[17];
  const float* d4w = (const float*)d_in[18]; const float* d4b = (const float*)d_in[19];
  const float* d5w = (const float*)d_in[20]; const float* d5b = (const float*)d_in[21];

  float* out = (float*)d_out;
  float* recon  = out;                   // (8, 65536)
  float* qout   = out + 524288;          // (8, 8192, 512)
  float* codes  = out + 34078720;        // (8, 8192) as float
  float* losses = out + 34144256;        // [commitment, recon]

  float* A   = (float*)d_ws;             // 33554432 floats
  float* Bb  = A + 33554432;             // 33554432 floats
  float* t1  = Bb + 33554432;            // 65536
  float* cn  = t1 + 65536;               // 1024
  float* pc  = cn + 1024;                // 8192
  float* pr  = pc + 8192;                // 256

  // bf16 regions (reuse A/Bb halves):
  unsigned short* qb  = (unsigned short*)A;         // written by vq_k (A dead post-transpose)
  unsigned short* yb1 = (unsigned short*)Bb;
  unsigned short* yb2 = (unsigned short*)A;
  unsigned short* yb3 = (unsigned short*)(Bb + 16777216);
  unsigned short* yb4 = (unsigned short*)A;
  unsigned short* wsp   = (unsigned short*)(A + 16777216);
  unsigned short* zbuf  = wsp;
  unsigned short* wp1   = zbuf + 1024;
  unsigned short* wp2e  = wp1  + 1835008;
  unsigned short* wp2o  = wp2e + 917504;
  unsigned short* wp3e  = wp2o + 1048576;
  unsigned short* wp3o  = wp3e + 229376;
  unsigned short* wp4e  = wp3o + 262144;
  unsigned short* wp4o  = wp4e + 57344;

  dim3 blk(256);

  // ---- encoder (R6 structure + phased window; BIT-EXACT) ----
  conv1d_k<15,1,7,1><<<dim3(128,  4, 8), blk, 0, stream>>>(wave, e1w, e1b, A,   1,  64, 65536, 65536);
  conv1d_k<15,2,7,1><<<dim3( 64,  8, 8), blk, 0, stream>>>(A,    e2w, e2b, Bb, 64, 128, 65536, 32768);
  conv1d_k<15,2,7,1><<<dim3( 32, 16, 8), blk, 0, stream>>>(Bb,   e3w, e3b, A, 128, 256, 32768, 16384);
  conv1d_k<15,2,7,1><<<dim3( 16, 32, 8), blk, 0, stream>>>(A,    e4w, e4b, Bb,256, 512, 16384,  8192);
  conv1d_k< 7,1,3,0><<<dim3( 16, 32, 8), blk, 0, stream>>>(Bb,   e5w, e5b, A, 512, 512,  8192,  8192);

  // ---- VQ (f32 numpy expression; BIT-EXACT) + fused bf16 q emit ----
  transpose_k<<<dim3(256, 16, 8), dim3(32, 8), 0, stream>>>(A, Bb, 512, 8192);
  rowsumsq_k<<<dim3(256), blk, 0, stream>>>(Bb, t1, 65536);
  rowsumsq_k<<<dim3(4),   blk, 0, stream>>>(cb, cn, 1024);
  vq_k<<<dim3(8192), blk, 0, stream>>>(Bb, cb, t1, cn, qout, qb, codes, pc);

  // ---- decoder prep ----
  zero_zbuf_k<<<dim3(4), blk, 0, stream>>>(zbuf);
  prepack_w_k<<<dim3(7168), blk, 0, stream>>>(d1w, wp1, 512, 512, 7, 7, 0, 1);
  prepack_w_k<<<dim3(3584), blk, 0, stream>>>(d2w, wp2e, 512, 256, 15, 7, 1, 2);
  prepack_w_k<<<dim3(4096), blk, 0, stream>>>(d2w, wp2o, 512, 256, 15, 8, 0, 2);
  prepack_w_k<<<dim3( 896), blk, 0, stream>>>(d3w, wp3e, 256, 128, 15, 7, 1, 2);
  prepack_w_k<<<dim3(1024), blk, 0, stream>>>(d3w, wp3o, 256, 128, 15, 8, 0, 2);
  prepack_w_k<<<dim3( 224), blk, 0, stream>>>(d4w, wp4e, 128,  64, 15, 7, 1, 2);
  prepack_w_k<<<dim3( 256), blk, 0, stream>>>(d4w, wp4o, 128,  64, 15, 8, 0, 2);

  // ---- decoder (bf16 MFMA implicit GEMM) ----
  mfma_convt_k<<<dim3(128, 32, 8), blk, 0, stream>>>(qb,  wp1,  d1b, yb1, zbuf, 512, 512, 8192, 8192, 1, 0, 7, 3);
  mfma_convt_k<<<dim3(128, 16, 8), blk, 0, stream>>>(yb1, wp2e, d2b, yb2, zbuf, 512, 256, 8192, 16384, 2, 0, 7, 3);
  mfma_convt_k<<<dim3(128, 16, 8), blk, 0, stream>>>(yb1, wp2o, d2b, yb2, zbuf, 512, 256, 8192, 16384, 2, 1, 8, 4);
  mfma_convt_k<<<dim3(256,  8, 8), blk, 0, stream>>>(yb2, wp3e, d3b, yb3, zbuf, 256, 128, 16384, 32768, 2, 0, 7, 3);
  mfma_convt_k<<<dim3(256,  8, 8), blk, 0, stream>>>(yb2, wp3o, d3b, yb3, zbuf, 256, 128, 16384, 32768, 2, 1, 8, 4);
  mfma_convt_k<<<dim3(512,  4, 8), blk, 0, stream>>>(yb3, wp4e, d4b, yb4, zbuf, 128,  64, 32768, 65536, 2, 0, 7, 3);
  mfma_convt_k<<<dim3(512,  4, 8), blk, 0, stream>>>(yb3, wp4o, d4b, yb4, zbuf, 128,  64, 32768, 65536, 2, 1, 8, 4);
  convt_final_bf16_k<<<dim3(256, 8), blk, 0, stream>>>(yb4, d5w, d5b, recon);

  // ---- losses ----
  absdiff_part_k<<<dim3(256), blk, 0, stream>>>(recon, wave, pr);
  finalize_k<<<dim3(1), blk, 0, stream>>>(pc, pr, losses);
}

// Round 16
// 17997.130 us; speedup vs baseline: 1.4114x; 1.1663x over previous
//
#include <hip/hip_runtime.h>
#include <hip/hip_bf16.h>
#include <math.h>

#define DEV __device__ __forceinline__

typedef __attribute__((ext_vector_type(8))) short s16x8;   // 8 bf16 in 4 VGPRs
typedef __attribute__((ext_vector_type(4))) float f32x4;

// ELU matching numpy (encoder only): f64 expm1 + single f32 round.
DEV float elu_f(float v) { return v > 0.0f ? v : (float)expm1((double)v); }
// fast f32 ELU (decoder epilogue; accuracy uncritical)
DEV float elu_fast(float v) { return v > 0.0f ? v : expm1f(v); }

DEV unsigned short f2bf(float f) {
  unsigned u = __float_as_uint(f);
  return (unsigned short)((u + 0x7fffu + ((u >> 16) & 1u)) >> 16);
}
DEV float bf2f(unsigned short s) { return __uint_as_float(((unsigned)s) << 16); }

#define QC(Q, C) ((C) == 0 ? (Q).x : (C) == 1 ? (Q).y : (C) == 2 ? (Q).z : (Q).w)

// ---------------------------------------------------------------------------
// f32 forward conv1d (encoder — BIT-EXACT; R14 champion: VGPR 48, e4 4.41ms.
// Seven structural variants converge here — do not touch further).
// ---------------------------------------------------------------------------
template<int K, int S, int PAD, int ACT>
__global__ __launch_bounds__(256) void conv1d_k(
    const float* __restrict__ x, const float* __restrict__ w,
    const float* __restrict__ bias, float* __restrict__ y,
    int Cin, int Cout, int Lin, int Lout)
{
  constexpr int PT = 8;
  constexpr int W  = (PT - 1) * S + K;
  constexpr int M0 = (4 - (PAD & 3)) & 3;      // 1 for PAD 7/3
  constexpr int NQ = (M0 + W + 3) / 4;         // S2K15: 8, S1K15: 6, S1K7: 4
  constexpr int CC = 16;
  constexpr int KP = (K + 3) & ~3;
  constexpr bool PHASED = (S == 2 && K == 15);

  const int lane = threadIdx.x & 63;
  const int wv   = threadIdx.x >> 6;
  const int b    = blockIdx.z;
  const int cob  = blockIdx.y * 16;
  const int t0   = (blockIdx.x * 64 + lane) * PT;

  __shared__ __align__(16) float wl[16][CC][KP];

  float acc[4][PT];
  #pragma unroll
  for (int cc = 0; cc < 4; ++cc)
    #pragma unroll
    for (int g = 0; g < PT; ++g) acc[cc][g] = 0.0f;

  const float* xb  = x + (size_t)b * Cin * Lin;
  const int vbase = t0 * S - PAD - M0;
  const bool fast = (vbase >= 0) && (vbase + 4 * NQ <= Lin);

  float4 q0, q1, q2, q3, q4, q5, q6, q7;

#define XV(I) ((I) < 4 ? QC(q0,(I)&3) : (I) < 8 ? QC(q1,(I)&3) : (I) < 12 ? QC(q2,(I)&3) : \
               (I) < 16 ? QC(q3,(I)&3) : (I) < 20 ? QC(q4,(I)&3) : (I) < 24 ? QC(q5,(I)&3) : \
               (I) < 28 ? QC(q6,(I)&3) : QC(q7,(I)&3))
#define LD4(Q, OFF)                                                           \
  if (fast) { Q = *(const float4*)(xpB + vbase + (OFF)); }                    \
  else {                                                                      \
    int i0_ = vbase + (OFF);                                                  \
    Q.x = (i0_ + 0 >= 0 && i0_ + 0 < Lin) ? xpB[i0_ + 0] : 0.0f;              \
    Q.y = (i0_ + 1 >= 0 && i0_ + 1 < Lin) ? xpB[i0_ + 1] : 0.0f;              \
    Q.z = (i0_ + 2 >= 0 && i0_ + 2 < Lin) ? xpB[i0_ + 2] : 0.0f;              \
    Q.w = (i0_ + 3 >= 0 && i0_ + 3 < Lin) ? xpB[i0_ + 3] : 0.0f;              \
  }

  for (int c0 = 0; c0 < Cin; c0 += CC) {
    const int cn = (Cin - c0 < CC) ? (Cin - c0) : CC;
    __syncthreads();
    for (int i = threadIdx.x; i < 16 * cn * K; i += 256) {
      int cc  = i / (cn * K);
      int rem = i - cc * (cn * K);
      int ci  = rem / K;
      int k   = rem - ci * K;
      wl[cc][ci][k] = w[((size_t)(cob + cc) * Cin + (c0 + ci)) * K + k];
    }
    __syncthreads();
    #pragma unroll 1
    for (int ci = 0; ci < cn; ++ci) {
      const float* xpB = xb + (size_t)(c0 + ci) * Lin;
      if constexpr (PHASED) {
        LD4(q0, 0) LD4(q1, 4) LD4(q2, 8) LD4(q3, 12) LD4(q4, 16) LD4(q5, 20)
        // phase A: k = 0..7 (window floats 1..22 -> q0..q5)
        #pragma unroll
        for (int cc = 0; cc < 4; ++cc) {
          float wk[8];
          { float4 t = *(const float4*)&wl[wv*4+cc][ci][0];
            wk[0]=t.x; wk[1]=t.y; wk[2]=t.z; wk[3]=t.w; }
          { float4 t = *(const float4*)&wl[wv*4+cc][ci][4];
            wk[4]=t.x; wk[5]=t.y; wk[6]=t.z; wk[7]=t.w; }
          #pragma unroll
          for (int k = 0; k < 8; ++k) {
            #pragma unroll
            for (int g = 0; g < 8; ++g)
              acc[cc][g] = fmaf(wk[k], XV(1 + 2*g + k), acc[cc][g]);
          }
        }
        LD4(q6, 24) LD4(q7, 28)
        // phase B: k = 8..14 (window floats 9..29 -> q2..q7; q0,q1 dead)
        #pragma unroll
        for (int cc = 0; cc < 4; ++cc) {
          float wk[7];
          { float4 t = *(const float4*)&wl[wv*4+cc][ci][8];
            wk[0]=t.x; wk[1]=t.y; wk[2]=t.z; wk[3]=t.w; }
          { float4 t = *(const float4*)&wl[wv*4+cc][ci][12];
            wk[4]=t.x; wk[5]=t.y; wk[6]=t.z; }
          #pragma unroll
          for (int k = 8; k < 15; ++k) {
            #pragma unroll
            for (int g = 0; g < 8; ++g)
              acc[cc][g] = fmaf(wk[k-8], XV(1 + 2*g + k), acc[cc][g]);
          }
        }
      } else {
        LD4(q0, 0) LD4(q1, 4) LD4(q2, 8) LD4(q3, 12)
        if constexpr (NQ > 4) { LD4(q4, 16) LD4(q5, 20) }
        #pragma unroll
        for (int cc = 0; cc < 4; ++cc) {
          float wk[KP];
          const float4* wq4 = (const float4*)(&wl[wv*4+cc][ci][0]);
          #pragma unroll
          for (int q4i = 0; q4i < KP/4; ++q4i) {
            float4 t = wq4[q4i];
            wk[4*q4i+0]=t.x; wk[4*q4i+1]=t.y; wk[4*q4i+2]=t.z; wk[4*q4i+3]=t.w;
          }
          #pragma unroll
          for (int k = 0; k < K; ++k) {
            #pragma unroll
            for (int g = 0; g < 8; ++g)
              acc[cc][g] = fmaf(wk[k], XV(M0 + g*S + k), acc[cc][g]);
          }
        }
      }
    }
  }
#undef XV
#undef LD4

  #pragma unroll
  for (int cc = 0; cc < 4; ++cc) {
    const int co = cob + wv * 4 + cc;
    const float bv = bias[co];
    float res[PT];
    #pragma unroll
    for (int g = 0; g < PT; ++g) {
      float v = acc[cc][g] + bv;
      if (ACT == 1) v = elu_f(v);
      res[g] = v;
    }
    float* yp = y + ((size_t)b * Cout + co) * Lout + t0;
    *(float4*)(yp)     = make_float4(res[0], res[1], res[2], res[3]);
    *(float4*)(yp + 4) = make_float4(res[4], res[5], res[6], res[7]);
  }
}

// ---------------------------------------------------------------------------
// Batched 2D transpose: in (B, R, S) -> out (B, S, R).
// ---------------------------------------------------------------------------
__global__ __launch_bounds__(256) void transpose_k(
    const float* __restrict__ in, float* __restrict__ out, int R, int S_)
{
  __shared__ float tile[32][33];
  const int b  = blockIdx.z;
  const int r0 = blockIdx.y * 32;
  const int s0 = blockIdx.x * 32;
  const float* ib = in + (size_t)b * R * S_;
  float* ob = out + (size_t)b * R * S_;
  const int tx = threadIdx.x, ty = threadIdx.y;
  #pragma unroll
  for (int i = 0; i < 32; i += 8)
    tile[ty + i][tx] = ib[(size_t)(r0 + ty + i) * S_ + s0 + tx];
  __syncthreads();
  #pragma unroll
  for (int i = 0; i < 32; i += 8)
    ob[(size_t)(s0 + ty + i) * R + r0 + tx] = tile[tx][ty + i];
}

// ---------------------------------------------------------------------------
// numpy-pairwise-identical f32 sum of squares over 512 contiguous floats.
// ---------------------------------------------------------------------------
DEV float np_sumsq_128(const float* a) {
  float r[8];
  #pragma unroll
  for (int j = 0; j < 8; ++j) r[j] = __fmul_rn(a[j], a[j]);
  #pragma unroll
  for (int i = 8; i < 128; i += 8) {
    #pragma unroll
    for (int j = 0; j < 8; ++j)
      r[j] = __fadd_rn(r[j], __fmul_rn(a[i + j], a[i + j]));
  }
  float s01 = __fadd_rn(r[0], r[1]), s23 = __fadd_rn(r[2], r[3]);
  float s45 = __fadd_rn(r[4], r[5]), s67 = __fadd_rn(r[6], r[7]);
  return __fadd_rn(__fadd_rn(s01, s23), __fadd_rn(s45, s67));
}
DEV float np_sumsq_512(const float* a) {
  float s0 = np_sumsq_128(a);
  float s1 = np_sumsq_128(a + 128);
  float s2 = np_sumsq_128(a + 256);
  float s3 = np_sumsq_128(a + 384);
  return __fadd_rn(__fadd_rn(s0, s1), __fadd_rn(s2, s3));
}

__global__ __launch_bounds__(256) void rowsumsq_k(
    const float* __restrict__ in, float* __restrict__ out, int nrows)
{
  const int r = blockIdx.x * 256 + threadIdx.x;
  if (r >= nrows) return;
  out[r] = np_sumsq_512(in + (size_t)r * 512);
}

// ---------------------------------------------------------------------------
// Codebook prepack for coalesced VQ loads: cb[k][d] -> cbp4[d/4][k][d%4]
// (lane k then reads 16B at 16B lane stride -> one coalesced 1KB transaction).
// ---------------------------------------------------------------------------
__global__ __launch_bounds__(256) void prepack_cb_k(
    const float* __restrict__ cb, float* __restrict__ cbp4)
{
  int id = blockIdx.x * 256 + threadIdx.x;     // over 1024*512
  int k = id >> 9, d = id & 511;
  cbp4[(size_t)(d >> 2) * 4096 + k * 4 + (d & 3)] = cb[id];
}

// ---------------------------------------------------------------------------
// VQ, numpy-f32-faithful (BIT-EXACT dist/argmin: FMA sequence per acc is
// identical to all passing rounds — only the codebook LOAD ADDRESSES changed
// to the coalesced cbp4 layout). Emits q f32 + q bf16 + codes + commit part.
// ---------------------------------------------------------------------------
__global__ __launch_bounds__(256) void vq_k(
    const float* __restrict__ embT, const float* __restrict__ cb,
    const float* __restrict__ cbp4,
    const float* __restrict__ t1, const float* __restrict__ cnorm,
    float* __restrict__ qout, unsigned short* __restrict__ qb,
    float* __restrict__ codes, float* __restrict__ pc)
{
  __shared__ __align__(16) float xs[8][512];
  __shared__ float rv[4][8];
  __shared__ int   ri[4][8];
  __shared__ int   bidx[8];
  __shared__ float cred[4];

  const int tid  = threadIdx.x;
  const int row0 = blockIdx.x * 8;

  for (int i = tid * 4; i < 4096; i += 1024)
    *(float4*)((float*)xs + i) = *(const float4*)(embT + (size_t)row0 * 512 + i);
  __syncthreads();

  float acc[4][8];
  #pragma unroll
  for (int j = 0; j < 4; ++j)
    #pragma unroll
    for (int r = 0; r < 8; ++r) acc[j][r] = 0.0f;

  const float* cb4 = cbp4 + (size_t)tid * 4;   // lane base (k*4, k=tid)
  #pragma unroll 1
  for (int d0 = 0; d0 < 512; d0 += 4) {
    float4 xv[8];
    #pragma unroll
    for (int r = 0; r < 8; ++r) xv[r] = *(const float4*)&xs[r][d0];
    const float* cbd = cb4 + (size_t)(d0 >> 2) * 4096;
    #pragma unroll
    for (int j = 0; j < 4; ++j) {
      float4 cv = *(const float4*)(cbd + j * 1024);   // k = tid + 256*j
      #pragma unroll
      for (int r = 0; r < 8; ++r) {
        acc[j][r] = fmaf(cv.x, xv[r].x, acc[j][r]);
        acc[j][r] = fmaf(cv.y, xv[r].y, acc[j][r]);
        acc[j][r] = fmaf(cv.z, xv[r].z, acc[j][r]);
        acc[j][r] = fmaf(cv.w, xv[r].w, acc[j][r]);
      }
    }
  }

  float cnj[4];
  #pragma unroll
  for (int j = 0; j < 4; ++j) cnj[j] = cnorm[tid + 256 * j];
  float t1r[8];
  #pragma unroll
  for (int r = 0; r < 8; ++r) t1r[r] = t1[row0 + r];

  const int lane = tid & 63, wv = tid >> 6;
  #pragma unroll 1
  for (int r = 0; r < 8; ++r) {
    float bv = 0.0f; int bi = 0;
    #pragma unroll
    for (int j = 0; j < 4; ++j) {
      float dv = __fsub_rn(__fadd_rn(t1r[r], cnj[j]), __fmul_rn(2.0f, acc[j][r]));
      int ki = tid + 256 * j;
      if (j == 0 || dv < bv || (dv == bv && ki < bi)) { bv = dv; bi = ki; }
    }
    #pragma unroll
    for (int off = 32; off; off >>= 1) {
      float ov = __shfl_xor(bv, off);
      int   oi = __shfl_xor(bi, off);
      if (ov < bv || (ov == bv && oi < bi)) { bv = ov; bi = oi; }
    }
    if (lane == 0) { rv[wv][r] = bv; ri[wv][r] = bi; }
  }
  __syncthreads();
  if (tid < 8) {
    float bv = rv[0][tid]; int bi = ri[0][tid];
    #pragma unroll
    for (int wq = 1; wq < 4; ++wq) {
      float ov = rv[wq][tid]; int oi = ri[wq][tid];
      if (ov < bv || (ov == bv && oi < bi)) { bv = ov; bi = oi; }
    }
    bidx[tid] = bi;
    codes[row0 + tid] = (float)bi;
  }
  __syncthreads();

  float csum = 0.0f;
  for (int i = tid * 4; i < 4096; i += 1024) {
    int r = i >> 9, d = i & 511;
    float4 qv = *(const float4*)(cb + (size_t)bidx[r] * 512 + d);
    *(float4*)(qout + (size_t)(row0 + r) * 512 + d) = qv;
    ushort4 ob;
    ob.x = f2bf(qv.x); ob.y = f2bf(qv.y); ob.z = f2bf(qv.z); ob.w = f2bf(qv.w);
    *(ushort4*)(qb + (size_t)(row0 + r) * 512 + d) = ob;
    float dx = qv.x - xs[r][d],     dy = qv.y - xs[r][d + 1];
    float dz = qv.z - xs[r][d + 2], dw = qv.w - xs[r][d + 3];
    csum += dx * dx + dy * dy + dz * dz + dw * dw;
  }
  #pragma unroll
  for (int off = 32; off; off >>= 1) csum += __shfl_xor(csum, off);
  if (lane == 0) cred[wv] = csum;
  __syncthreads();
  if (tid == 0) pc[blockIdx.x] = cred[0] + cred[1] + cred[2] + cred[3];
}

__global__ __launch_bounds__(256) void zero_zbuf_k(unsigned short* z) {
  z[blockIdx.x * 256 + threadIdx.x] = 0;
}

// ---------------------------------------------------------------------------
// Decoder weight prepack: w [Cin][Cout][K] f32 -> wp bf16 (B-frag contiguous).
// ---------------------------------------------------------------------------
__global__ __launch_bounds__(256) void prepack_w_k(
    const float* __restrict__ w, unsigned short* __restrict__ wp,
    int Cin, int Cout, int K, int T, int m0, int ms)
{
  int id = blockIdx.x * 256 + threadIdx.x;
  int tot = T * Cin * Cout;
  if (id >= tot) return;
  int jj  = id / (Cin * Cout);
  int rem = id - jj * (Cin * Cout);
  int ci  = rem / Cout;
  int co  = rem - ci * Cout;
  int m   = m0 + ms * jj;
  float v = w[((size_t)ci * Cout + co) * K + m];
  size_t dst = ((size_t)((jj * (Cin >> 5) + (ci >> 5)) * 4 + ((ci & 31) >> 3))) * ((size_t)Cout * 8)
             + (size_t)co * 8 + (ci & 7);
  wp[dst] = f2bf(v);
}

// ---------------------------------------------------------------------------
// MFMA implicit-GEMM transposed-conv (one parity): bf16 in/out, f32 accum.
// ---------------------------------------------------------------------------
__global__ __launch_bounds__(256) void mfma_convt_k(
    const unsigned short* __restrict__ xb, const unsigned short* __restrict__ wp,
    const float* __restrict__ bias, unsigned short* __restrict__ yb,
    const unsigned short* __restrict__ zbuf,
    int Cin, int Cout, int Lin, int Lout, int S, int p, int T, int OFF0)
{
  const int lane = threadIdx.x & 63;
  const int wv   = threadIdx.x >> 6;
  const int r    = lane & 15;
  const int g    = lane >> 4;
  const int b    = blockIdx.z;
  const int u0   = blockIdx.x * 64 + wv * 16;
  const int co0  = blockIdx.y * 16;
  const int CB   = Cin >> 5;

  f32x4 acc = {0.f, 0.f, 0.f, 0.f};
  const unsigned short* xbb = xb + (size_t)b * Lin * Cin + g * 8;
  const unsigned short* zp  = zbuf + g * 8;
  const unsigned short* wpb = wp + (size_t)(co0 + r) * 8 + (size_t)g * Cout * 8;
  const size_t bstride = (size_t)4 * Cout * 8;

  const float bv = bias[co0 + r];

  #pragma unroll 1
  for (int jj = 0; jj < T; ++jj) {
    int u = u0 + r + OFF0 - jj;
    bool val = (u >= 0) && (u < Lin);
    const unsigned short* ap = val ? (xbb + (size_t)u * Cin) : zp;
    const unsigned short* bp = wpb + (size_t)jj * CB * bstride;
    #pragma unroll 2
    for (int cb = 0; cb < CB; ++cb) {
      s16x8 a  = *(const s16x8*)(ap + cb * 32);
      s16x8 bf = *(const s16x8*)(bp + (size_t)cb * bstride);
      acc = __builtin_amdgcn_mfma_f32_16x16x32_bf16(a, bf, acc, 0, 0, 0);
    }
  }

  #pragma unroll
  for (int reg = 0; reg < 4; ++reg) {
    int u  = u0 + g * 4 + reg;
    int o  = S * u + p;
    float v = elu_fast(acc[reg] + bv);
    yb[((size_t)b * Lout + o) * Cout + (co0 + r)] = f2bf(v);
  }
}

// ---------------------------------------------------------------------------
// Final decoder layer from bf16 row-major input [B][65536][64]: tanh conv.
// ---------------------------------------------------------------------------
__global__ __launch_bounds__(256) void convt_final_bf16_k(
    const unsigned short* __restrict__ xb, const float* __restrict__ w,
    const float* __restrict__ bias, float* __restrict__ y)
{
  __shared__ float wl[64][16];
  for (int i = threadIdx.x; i < 64 * 15; i += 256) wl[i / 15][i % 15] = w[i];
  __syncthreads();
  const int b = blockIdx.y;
  const int o = blockIdx.x * 256 + threadIdx.x;
  float acc = 0.0f;
  #pragma unroll 1
  for (int m = 0; m < 15; ++m) {
    int i = o + 7 - m;
    if (i < 0 || i >= 65536) continue;
    const unsigned short* xp = xb + ((size_t)b * 65536 + i) * 64;
    #pragma unroll
    for (int c8 = 0; c8 < 8; ++c8) {
      s16x8 xv = *(const s16x8*)(xp + c8 * 8);
      #pragma unroll
      for (int k = 0; k < 8; ++k)
        acc = fmaf(wl[c8 * 8 + k][m], bf2f((unsigned short)xv[k]), acc);
    }
  }
  y[(size_t)b * 65536 + o] = tanhf(acc + bias[0]);
}

// ---------------------------------------------------------------------------
// recon |diff| partial reduce + final losses
// ---------------------------------------------------------------------------
__global__ __launch_bounds__(256) void absdiff_part_k(
    const float* __restrict__ a, const float* __restrict__ b, float* __restrict__ pr)
{
  __shared__ float cred[4];
  const int tid  = threadIdx.x;
  const int base = blockIdx.x * 2048;
  float s = 0.0f;
  for (int i = tid * 4; i < 2048; i += 1024) {
    float4 x = *(const float4*)(a + base + i);
    float4 y = *(const float4*)(b + base + i);
    s += fabsf(x.x - y.x) + fabsf(x.y - y.y) + fabsf(x.z - y.z) + fabsf(x.w - y.w);
  }
  #pragma unroll
  for (int off = 32; off; off >>= 1) s += __shfl_xor(s, off);
  const int lane = tid & 63, wv = tid >> 6;
  if (lane == 0) cred[wv] = s;
  __syncthreads();
  if (tid == 0) pr[blockIdx.x] = cred[0] + cred[1] + cred[2] + cred[3];
}

__global__ __launch_bounds__(256) void finalize_k(
    const float* __restrict__ pc, const float* __restrict__ pr, float* __restrict__ outp)
{
  __shared__ float red[4];
  const int tid = threadIdx.x;
  const int lane = tid & 63, wv = tid >> 6;

  float s = 0.0f;
  for (int i = tid; i < 8192; i += 256) s += pc[i];
  #pragma unroll
  for (int off = 32; off; off >>= 1) s += __shfl_xor(s, off);
  if (lane == 0) red[wv] = s;
  __syncthreads();
  if (tid == 0) outp[0] = 0.25f * (red[0] + red[1] + red[2] + red[3]) / 33554432.0f;
  __syncthreads();

  float s2 = 0.0f;
  if (tid < 64) {
    for (int i = tid; i < 256; i += 64) s2 += pr[i];
    #pragma unroll
    for (int off = 32; off; off >>= 1) s2 += __shfl_xor(s2, off);
    if (tid == 0) outp[1] = s2 / 524288.0f;
  }
}

// ---------------------------------------------------------------------------
extern "C" void kernel_launch(void* const* d_in, const int* in_sizes, int n_in,
                              void* d_out, int out_size, void* d_ws, size_t ws_size,
                              hipStream_t stream) {
  const float* wave = (const float*)d_in[0];
  const float* e1w = (const float*)d_in[1];  const float* e1b = (const float*)d_in[2];
  const float* e2w = (const float*)d_in[3];  const float* e2b = (const float*)d_in[4];
  const float* e3w = (const float*)d_in[5];  const float* e3b = (const float*)d_in[6];
  const float* e4w = (const float*)d_in[7];  const float* e4b = (const float*)d_in[8];
  const float* e5w = (const float*)d_in[9];  const float* e5b = (const float*)d_in[10];
  const float* cb  = (const float*)d_in[11];
  const float* d1w = (const float*)d_in[12]; const float* d1b = (const float*)d_in[13];
  const float* d2w = (const float*)d_in[14]; const float* d2b = (const float*)d_in[15];
  const float* d3w = (const float*)d_in[16]; const float* d3b = (const float*)d_in[17];
  const float* d4w = (const float*)d_in[18]; const float* d4b = (const float*)d_in[19];
  const float* d5w = (const float*)d_in[20]; const float* d5b = (const float*)d_in[21];

  float* out = (float*)d_out;
  float* recon  = out;                   // (8, 65536)
  float* qout   = out + 524288;          // (8, 8192, 512)
  float* codes  = out + 34078720;        // (8, 8192) as float
  float* losses = out + 34144256;        // [commitment, recon]

  float* A   = (float*)d_ws;             // 33554432 floats
  float* Bb  = A + 33554432;             // 33554432 floats
  float* t1  = Bb + 33554432;            // 65536
  float* cn  = t1 + 65536;               // 1024
  float* pc  = cn + 1024;                // 8192
  float* pr  = pc + 8192;                // 256
  float* cbp4 = pr + 256;                // 524288 (packed codebook, 2MB)

  // bf16 regions (reuse A/Bb halves):
  unsigned short* qb  = (unsigned short*)A;         // written by vq_k (A dead post-transpose)
  unsigned short* yb1 = (unsigned short*)Bb;
  unsigned short* yb2 = (unsigned short*)A;
  unsigned short* yb3 = (unsigned short*)(Bb + 16777216);
  unsigned short* yb4 = (unsigned short*)A;
  unsigned short* wsp   = (unsigned short*)(A + 16777216);
  unsigned short* zbuf  = wsp;
  unsigned short* wp1   = zbuf + 1024;
  unsigned short* wp2e  = wp1  + 1835008;
  unsigned short* wp2o  = wp2e + 917504;
  unsigned short* wp3e  = wp2o + 1048576;
  unsigned short* wp3o  = wp3e + 229376;
  unsigned short* wp4e  = wp3o + 262144;
  unsigned short* wp4o  = wp4e + 57344;

  dim3 blk(256);

  // ---- encoder (R14 champion; BIT-EXACT) ----
  conv1d_k<15,1,7,1><<<dim3(128,  4, 8), blk, 0, stream>>>(wave, e1w, e1b, A,   1,  64, 65536, 65536);
  conv1d_k<15,2,7,1><<<dim3( 64,  8, 8), blk, 0, stream>>>(A,    e2w, e2b, Bb, 64, 128, 65536, 32768);
  conv1d_k<15,2,7,1><<<dim3( 32, 16, 8), blk, 0, stream>>>(Bb,   e3w, e3b, A, 128, 256, 32768, 16384);
  conv1d_k<15,2,7,1><<<dim3( 16, 32, 8), blk, 0, stream>>>(A,    e4w, e4b, Bb,256, 512, 16384,  8192);
  conv1d_k< 7,1,3,0><<<dim3( 16, 32, 8), blk, 0, stream>>>(Bb,   e5w, e5b, A, 512, 512,  8192,  8192);

  // ---- VQ (BIT-EXACT expression; coalesced codebook layout) ----
  transpose_k<<<dim3(256, 16, 8), dim3(32, 8), 0, stream>>>(A, Bb, 512, 8192);
  rowsumsq_k<<<dim3(256), blk, 0, stream>>>(Bb, t1, 65536);
  rowsumsq_k<<<dim3(4),   blk, 0, stream>>>(cb, cn, 1024);
  prepack_cb_k<<<dim3(2048), blk, 0, stream>>>(cb, cbp4);
  vq_k<<<dim3(8192), blk, 0, stream>>>(Bb, cb, cbp4, t1, cn, qout, qb, codes, pc);

  // ---- decoder prep ----
  zero_zbuf_k<<<dim3(4), blk, 0, stream>>>(zbuf);
  prepack_w_k<<<dim3(7168), blk, 0, stream>>>(d1w, wp1, 512, 512, 7, 7, 0, 1);
  prepack_w_k<<<dim3(3584), blk, 0, stream>>>(d2w, wp2e, 512, 256, 15, 7, 1, 2);
  prepack_w_k<<<dim3(4096), blk, 0, stream>>>(d2w, wp2o, 512, 256, 15, 8, 0, 2);
  prepack_w_k<<<dim3( 896), blk, 0, stream>>>(d3w, wp3e, 256, 128, 15, 7, 1, 2);
  prepack_w_k<<<dim3(1024), blk, 0, stream>>>(d3w, wp3o, 256, 128, 15, 8, 0, 2);
  prepack_w_k<<<dim3( 224), blk, 0, stream>>>(d4w, wp4e, 128,  64, 15, 7, 1, 2);
  prepack_w_k<<<dim3( 256), blk, 0, stream>>>(d4w, wp4o, 128,  64, 15, 8, 0, 2);

  // ---- decoder (bf16 MFMA implicit GEMM) ----
  mfma_convt_k<<<dim3(128, 32, 8), blk, 0, stream>>>(qb,  wp1,  d1b, yb1, zbuf, 512, 512, 8192, 8192, 1, 0, 7, 3);
  mfma_convt_k<<<dim3(128, 16, 8), blk, 0, stream>>>(yb1, wp2e, d2b, yb2, zbuf, 512, 256, 8192, 16384, 2, 0, 7, 3);
  mfma_convt_k<<<dim3(128, 16, 8), blk, 0, stream>>>(yb1, wp2o, d2b, yb2, zbuf, 512, 256, 8192, 16384, 2, 1, 8, 4);
  mfma_convt_k<<<dim3(256,  8, 8), blk, 0, stream>>>(yb2, wp3e, d3b, yb3, zbuf, 256, 128, 16384, 32768, 2, 0, 7, 3);
  mfma_convt_k<<<dim3(256,  8, 8), blk, 0, stream>>>(yb2, wp3o, d3b, yb3, zbuf, 256, 128, 16384, 32768, 2, 1, 8, 4);
  mfma_convt_k<<<dim3(512,  4, 8), blk, 0, stream>>>(yb3, wp4e, d4b, yb4, zbuf, 128,  64, 32768, 65536, 2, 0, 7, 3);
  mfma_convt_k<<<dim3(512,  4, 8), blk, 0, stream>>>(yb3, wp4o, d4b, yb4, zbuf, 128,  64, 32768, 65536, 2, 1, 8, 4);
  convt_final_bf16_k<<<dim3(256, 8), blk, 0, stream>>>(yb4, d5w, d5b, recon);

  // ---- losses ----
  absdiff_part_k<<<dim3(256), blk, 0, stream>>>(recon, wave, pr);
  finalize_k<<<dim3(1), blk, 0, stream>>>(pc, pr, losses);
}

// Round 17
// 17047.105 us; speedup vs baseline: 1.4901x; 1.0557x over previous
//
#include <hip/hip_runtime.h>
#include <hip/hip_bf16.h>
#include <math.h>

#define DEV __device__ __forceinline__

typedef __attribute__((ext_vector_type(8))) short s16x8;   // 8 bf16 in 4 VGPRs
typedef __attribute__((ext_vector_type(4))) float f32x4;

// ELU matching numpy (encoder only): f64 expm1 + single f32 round.
DEV float elu_f(float v) { return v > 0.0f ? v : (float)expm1((double)v); }
// fast f32 ELU (decoder epilogue; accuracy uncritical)
DEV float elu_fast(float v) { return v > 0.0f ? v : expm1f(v); }

DEV unsigned short f2bf(float f) {
  unsigned u = __float_as_uint(f);
  return (unsigned short)((u + 0x7fffu + ((u >> 16) & 1u)) >> 16);
}
DEV float bf2f(unsigned short s) { return __uint_as_float(((unsigned)s) << 16); }

#define QC(Q, C) ((C) == 0 ? (Q).x : (C) == 1 ? (Q).y : (C) == 2 ? (Q).z : (Q).w)

// ---------------------------------------------------------------------------
// f32 forward conv1d (encoder — BIT-EXACT; R14 champion. Do not touch).
// ---------------------------------------------------------------------------
template<int K, int S, int PAD, int ACT>
__global__ __launch_bounds__(256) void conv1d_k(
    const float* __restrict__ x, const float* __restrict__ w,
    const float* __restrict__ bias, float* __restrict__ y,
    int Cin, int Cout, int Lin, int Lout)
{
  constexpr int PT = 8;
  constexpr int W  = (PT - 1) * S + K;
  constexpr int M0 = (4 - (PAD & 3)) & 3;      // 1 for PAD 7/3
  constexpr int NQ = (M0 + W + 3) / 4;         // S2K15: 8, S1K15: 6, S1K7: 4
  constexpr int CC = 16;
  constexpr int KP = (K + 3) & ~3;
  constexpr bool PHASED = (S == 2 && K == 15);

  const int lane = threadIdx.x & 63;
  const int wv   = threadIdx.x >> 6;
  const int b    = blockIdx.z;
  const int cob  = blockIdx.y * 16;
  const int t0   = (blockIdx.x * 64 + lane) * PT;

  __shared__ __align__(16) float wl[16][CC][KP];

  float acc[4][PT];
  #pragma unroll
  for (int cc = 0; cc < 4; ++cc)
    #pragma unroll
    for (int g = 0; g < PT; ++g) acc[cc][g] = 0.0f;

  const float* xb  = x + (size_t)b * Cin * Lin;
  const int vbase = t0 * S - PAD - M0;
  const bool fast = (vbase >= 0) && (vbase + 4 * NQ <= Lin);

  float4 q0, q1, q2, q3, q4, q5, q6, q7;

#define XV(I) ((I) < 4 ? QC(q0,(I)&3) : (I) < 8 ? QC(q1,(I)&3) : (I) < 12 ? QC(q2,(I)&3) : \
               (I) < 16 ? QC(q3,(I)&3) : (I) < 20 ? QC(q4,(I)&3) : (I) < 24 ? QC(q5,(I)&3) : \
               (I) < 28 ? QC(q6,(I)&3) : QC(q7,(I)&3))
#define LD4(Q, OFF)                                                           \
  if (fast) { Q = *(const float4*)(xpB + vbase + (OFF)); }                    \
  else {                                                                      \
    int i0_ = vbase + (OFF);                                                  \
    Q.x = (i0_ + 0 >= 0 && i0_ + 0 < Lin) ? xpB[i0_ + 0] : 0.0f;              \
    Q.y = (i0_ + 1 >= 0 && i0_ + 1 < Lin) ? xpB[i0_ + 1] : 0.0f;              \
    Q.z = (i0_ + 2 >= 0 && i0_ + 2 < Lin) ? xpB[i0_ + 2] : 0.0f;              \
    Q.w = (i0_ + 3 >= 0 && i0_ + 3 < Lin) ? xpB[i0_ + 3] : 0.0f;              \
  }

  for (int c0 = 0; c0 < Cin; c0 += CC) {
    const int cn = (Cin - c0 < CC) ? (Cin - c0) : CC;
    __syncthreads();
    for (int i = threadIdx.x; i < 16 * cn * K; i += 256) {
      int cc  = i / (cn * K);
      int rem = i - cc * (cn * K);
      int ci  = rem / K;
      int k   = rem - ci * K;
      wl[cc][ci][k] = w[((size_t)(cob + cc) * Cin + (c0 + ci)) * K + k];
    }
    __syncthreads();
    #pragma unroll 1
    for (int ci = 0; ci < cn; ++ci) {
      const float* xpB = xb + (size_t)(c0 + ci) * Lin;
      if constexpr (PHASED) {
        LD4(q0, 0) LD4(q1, 4) LD4(q2, 8) LD4(q3, 12) LD4(q4, 16) LD4(q5, 20)
        // phase A: k = 0..7 (window floats 1..22 -> q0..q5)
        #pragma unroll
        for (int cc = 0; cc < 4; ++cc) {
          float wk[8];
          { float4 t = *(const float4*)&wl[wv*4+cc][ci][0];
            wk[0]=t.x; wk[1]=t.y; wk[2]=t.z; wk[3]=t.w; }
          { float4 t = *(const float4*)&wl[wv*4+cc][ci][4];
            wk[4]=t.x; wk[5]=t.y; wk[6]=t.z; wk[7]=t.w; }
          #pragma unroll
          for (int k = 0; k < 8; ++k) {
            #pragma unroll
            for (int g = 0; g < 8; ++g)
              acc[cc][g] = fmaf(wk[k], XV(1 + 2*g + k), acc[cc][g]);
          }
        }
        LD4(q6, 24) LD4(q7, 28)
        // phase B: k = 8..14 (window floats 9..29 -> q2..q7; q0,q1 dead)
        #pragma unroll
        for (int cc = 0; cc < 4; ++cc) {
          float wk[7];
          { float4 t = *(const float4*)&wl[wv*4+cc][ci][8];
            wk[0]=t.x; wk[1]=t.y; wk[2]=t.z; wk[3]=t.w; }
          { float4 t = *(const float4*)&wl[wv*4+cc][ci][12];
            wk[4]=t.x; wk[5]=t.y; wk[6]=t.z; }
          #pragma unroll
          for (int k = 8; k < 15; ++k) {
            #pragma unroll
            for (int g = 0; g < 8; ++g)
              acc[cc][g] = fmaf(wk[k-8], XV(1 + 2*g + k), acc[cc][g]);
          }
        }
      } else {
        LD4(q0, 0) LD4(q1, 4) LD4(q2, 8) LD4(q3, 12)
        if constexpr (NQ > 4) { LD4(q4, 16) LD4(q5, 20) }
        #pragma unroll
        for (int cc = 0; cc < 4; ++cc) {
          float wk[KP];
          const float4* wq4 = (const float4*)(&wl[wv*4+cc][ci][0]);
          #pragma unroll
          for (int q4i = 0; q4i < KP/4; ++q4i) {
            float4 t = wq4[q4i];
            wk[4*q4i+0]=t.x; wk[4*q4i+1]=t.y; wk[4*q4i+2]=t.z; wk[4*q4i+3]=t.w;
          }
          #pragma unroll
          for (int k = 0; k < K; ++k) {
            #pragma unroll
            for (int g = 0; g < 8; ++g)
              acc[cc][g] = fmaf(wk[k], XV(M0 + g*S + k), acc[cc][g]);
          }
        }
      }
    }
  }
#undef XV
#undef LD4

  #pragma unroll
  for (int cc = 0; cc < 4; ++cc) {
    const int co = cob + wv * 4 + cc;
    const float bv = bias[co];
    float res[PT];
    #pragma unroll
    for (int g = 0; g < PT; ++g) {
      float v = acc[cc][g] + bv;
      if (ACT == 1) v = elu_f(v);
      res[g] = v;
    }
    float* yp = y + ((size_t)b * Cout + co) * Lout + t0;
    *(float4*)(yp)     = make_float4(res[0], res[1], res[2], res[3]);
    *(float4*)(yp + 4) = make_float4(res[4], res[5], res[6], res[7]);
  }
}

// ---------------------------------------------------------------------------
// Batched 2D transpose: in (B, R, S) -> out (B, S, R).
// ---------------------------------------------------------------------------
__global__ __launch_bounds__(256) void transpose_k(
    const float* __restrict__ in, float* __restrict__ out, int R, int S_)
{
  __shared__ float tile[32][33];
  const int b  = blockIdx.z;
  const int r0 = blockIdx.y * 32;
  const int s0 = blockIdx.x * 32;
  const float* ib = in + (size_t)b * R * S_;
  float* ob = out + (size_t)b * R * S_;
  const int tx = threadIdx.x, ty = threadIdx.y;
  #pragma unroll
  for (int i = 0; i < 32; i += 8)
    tile[ty + i][tx] = ib[(size_t)(r0 + ty + i) * S_ + s0 + tx];
  __syncthreads();
  #pragma unroll
  for (int i = 0; i < 32; i += 8)
    ob[(size_t)(s0 + ty + i) * R + r0 + tx] = tile[tx][ty + i];
}

// ---------------------------------------------------------------------------
// numpy-pairwise-identical f32 sum of squares over 512 contiguous floats.
// ---------------------------------------------------------------------------
DEV float np_sumsq_128(const float* a) {
  float r[8];
  #pragma unroll
  for (int j = 0; j < 8; ++j) r[j] = __fmul_rn(a[j], a[j]);
  #pragma unroll
  for (int i = 8; i < 128; i += 8) {
    #pragma unroll
    for (int j = 0; j < 8; ++j)
      r[j] = __fadd_rn(r[j], __fmul_rn(a[i + j], a[i + j]));
  }
  float s01 = __fadd_rn(r[0], r[1]), s23 = __fadd_rn(r[2], r[3]);
  float s45 = __fadd_rn(r[4], r[5]), s67 = __fadd_rn(r[6], r[7]);
  return __fadd_rn(__fadd_rn(s01, s23), __fadd_rn(s45, s67));
}
DEV float np_sumsq_512(const float* a) {
  float s0 = np_sumsq_128(a);
  float s1 = np_sumsq_128(a + 128);
  float s2 = np_sumsq_128(a + 256);
  float s3 = np_sumsq_128(a + 384);
  return __fadd_rn(__fadd_rn(s0, s1), __fadd_rn(s2, s3));
}

__global__ __launch_bounds__(256) void rowsumsq_k(
    const float* __restrict__ in, float* __restrict__ out, int nrows)
{
  const int r = blockIdx.x * 256 + threadIdx.x;
  if (r >= nrows) return;
  out[r] = np_sumsq_512(in + (size_t)r * 512);
}

// ---------------------------------------------------------------------------
// Codebook prepack for coalesced VQ loads: cb[k][d] -> cbp4[d/4][k][d%4].
// ---------------------------------------------------------------------------
__global__ __launch_bounds__(256) void prepack_cb_k(
    const float* __restrict__ cb, float* __restrict__ cbp4)
{
  int id = blockIdx.x * 256 + threadIdx.x;     // over 1024*512
  int k = id >> 9, d = id & 511;
  cbp4[(size_t)(d >> 2) * 4096 + k * 4 + (d & 3)] = cb[id];
}

// ---------------------------------------------------------------------------
// VQ, numpy-f32-faithful (BIT-EXACT dist/argmin; coalesced cbp4 layout).
// ---------------------------------------------------------------------------
__global__ __launch_bounds__(256) void vq_k(
    const float* __restrict__ embT, const float* __restrict__ cb,
    const float* __restrict__ cbp4,
    const float* __restrict__ t1, const float* __restrict__ cnorm,
    float* __restrict__ qout, unsigned short* __restrict__ qb,
    float* __restrict__ codes, float* __restrict__ pc)
{
  __shared__ __align__(16) float xs[8][512];
  __shared__ float rv[4][8];
  __shared__ int   ri[4][8];
  __shared__ int   bidx[8];
  __shared__ float cred[4];

  const int tid  = threadIdx.x;
  const int row0 = blockIdx.x * 8;

  for (int i = tid * 4; i < 4096; i += 1024)
    *(float4*)((float*)xs + i) = *(const float4*)(embT + (size_t)row0 * 512 + i);
  __syncthreads();

  float acc[4][8];
  #pragma unroll
  for (int j = 0; j < 4; ++j)
    #pragma unroll
    for (int r = 0; r < 8; ++r) acc[j][r] = 0.0f;

  const float* cb4 = cbp4 + (size_t)tid * 4;
  #pragma unroll 1
  for (int d0 = 0; d0 < 512; d0 += 4) {
    float4 xv[8];
    #pragma unroll
    for (int r = 0; r < 8; ++r) xv[r] = *(const float4*)&xs[r][d0];
    const float* cbd = cb4 + (size_t)(d0 >> 2) * 4096;
    #pragma unroll
    for (int j = 0; j < 4; ++j) {
      float4 cv = *(const float4*)(cbd + j * 1024);
      #pragma unroll
      for (int r = 0; r < 8; ++r) {
        acc[j][r] = fmaf(cv.x, xv[r].x, acc[j][r]);
        acc[j][r] = fmaf(cv.y, xv[r].y, acc[j][r]);
        acc[j][r] = fmaf(cv.z, xv[r].z, acc[j][r]);
        acc[j][r] = fmaf(cv.w, xv[r].w, acc[j][r]);
      }
    }
  }

  float cnj[4];
  #pragma unroll
  for (int j = 0; j < 4; ++j) cnj[j] = cnorm[tid + 256 * j];
  float t1r[8];
  #pragma unroll
  for (int r = 0; r < 8; ++r) t1r[r] = t1[row0 + r];

  const int lane = tid & 63, wv = tid >> 6;
  #pragma unroll 1
  for (int r = 0; r < 8; ++r) {
    float bv = 0.0f; int bi = 0;
    #pragma unroll
    for (int j = 0; j < 4; ++j) {
      float dv = __fsub_rn(__fadd_rn(t1r[r], cnj[j]), __fmul_rn(2.0f, acc[j][r]));
      int ki = tid + 256 * j;
      if (j == 0 || dv < bv || (dv == bv && ki < bi)) { bv = dv; bi = ki; }
    }
    #pragma unroll
    for (int off = 32; off; off >>= 1) {
      float ov = __shfl_xor(bv, off);
      int   oi = __shfl_xor(bi, off);
      if (ov < bv || (ov == bv && oi < bi)) { bv = ov; bi = oi; }
    }
    if (lane == 0) { rv[wv][r] = bv; ri[wv][r] = bi; }
  }
  __syncthreads();
  if (tid < 8) {
    float bv = rv[0][tid]; int bi = ri[0][tid];
    #pragma unroll
    for (int wq = 1; wq < 4; ++wq) {
      float ov = rv[wq][tid]; int oi = ri[wq][tid];
      if (ov < bv || (ov == bv && oi < bi)) { bv = ov; bi = oi; }
    }
    bidx[tid] = bi;
    codes[row0 + tid] = (float)bi;
  }
  __syncthreads();

  float csum = 0.0f;
  for (int i = tid * 4; i < 4096; i += 1024) {
    int r = i >> 9, d = i & 511;
    float4 qv = *(const float4*)(cb + (size_t)bidx[r] * 512 + d);
    *(float4*)(qout + (size_t)(row0 + r) * 512 + d) = qv;
    ushort4 ob;
    ob.x = f2bf(qv.x); ob.y = f2bf(qv.y); ob.z = f2bf(qv.z); ob.w = f2bf(qv.w);
    *(ushort4*)(qb + (size_t)(row0 + r) * 512 + d) = ob;
    float dx = qv.x - xs[r][d],     dy = qv.y - xs[r][d + 1];
    float dz = qv.z - xs[r][d + 2], dw = qv.w - xs[r][d + 3];
    csum += dx * dx + dy * dy + dz * dz + dw * dw;
  }
  #pragma unroll
  for (int off = 32; off; off >>= 1) csum += __shfl_xor(csum, off);
  if (lane == 0) cred[wv] = csum;
  __syncthreads();
  if (tid == 0) pc[blockIdx.x] = cred[0] + cred[1] + cred[2] + cred[3];
}

__global__ __launch_bounds__(256) void zero_zbuf_k(unsigned short* z) {
  z[blockIdx.x * 256 + threadIdx.x] = 0;
}

// ---------------------------------------------------------------------------
// Decoder weight prepack: w [Cin][Cout][K] f32 -> wp bf16 (B-frag contiguous).
// ---------------------------------------------------------------------------
__global__ __launch_bounds__(256) void prepack_w_k(
    const float* __restrict__ w, unsigned short* __restrict__ wp,
    int Cin, int Cout, int K, int T, int m0, int ms)
{
  int id = blockIdx.x * 256 + threadIdx.x;
  int tot = T * Cin * Cout;
  if (id >= tot) return;
  int jj  = id / (Cin * Cout);
  int rem = id - jj * (Cin * Cout);
  int ci  = rem / Cout;
  int co  = rem - ci * Cout;
  int m   = m0 + ms * jj;
  float v = w[((size_t)ci * Cout + co) * K + m];
  size_t dst = ((size_t)((jj * (Cin >> 5) + (ci >> 5)) * 4 + ((ci & 31) >> 3))) * ((size_t)Cout * 8)
             + (size_t)co * 8 + (ci & 7);
  wp[dst] = f2bf(v);
}

// ---------------------------------------------------------------------------
// MFMA implicit-GEMM transposed-conv (one parity): bf16 in/out, f32 accum.
// Round-17: each wave owns FOUR consecutive u-tiles (64 u rows) sharing one
// B-frag load per (jj,cb) -> 4 MFMA per B load (was 1). Per-output (jj,cb)
// accumulation order unchanged -> decoder output bit-identical to R16.
// grid: (Lu/256, Cout/16, B).
// ---------------------------------------------------------------------------
__global__ __launch_bounds__(256) void mfma_convt_k(
    const unsigned short* __restrict__ xb, const unsigned short* __restrict__ wp,
    const float* __restrict__ bias, unsigned short* __restrict__ yb,
    const unsigned short* __restrict__ zbuf,
    int Cin, int Cout, int Lin, int Lout, int S, int p, int T, int OFF0)
{
  const int lane = threadIdx.x & 63;
  const int wv   = threadIdx.x >> 6;
  const int r    = lane & 15;
  const int g    = lane >> 4;
  const int b    = blockIdx.z;
  const int u0   = blockIdx.x * 256 + wv * 64;   // wave covers u0 .. u0+63
  const int co0  = blockIdx.y * 16;
  const int CB   = Cin >> 5;

  f32x4 acc0 = {0.f,0.f,0.f,0.f}, acc1 = {0.f,0.f,0.f,0.f};
  f32x4 acc2 = {0.f,0.f,0.f,0.f}, acc3 = {0.f,0.f,0.f,0.f};
  const unsigned short* xbb = xb + (size_t)b * Lin * Cin + g * 8;
  const unsigned short* zp  = zbuf + g * 8;
  const unsigned short* wpb = wp + (size_t)(co0 + r) * 8 + (size_t)g * Cout * 8;
  const size_t bstride = (size_t)4 * Cout * 8;

  const float bv = bias[co0 + r];

  #pragma unroll 1
  for (int jj = 0; jj < T; ++jj) {
    const int ub = u0 + r + OFF0 - jj;
    const unsigned short* ap0; const unsigned short* ap1;
    const unsigned short* ap2; const unsigned short* ap3;
    { int u = ub +  0; ap0 = (u >= 0 && u < Lin) ? (xbb + (size_t)u * Cin) : zp; }
    { int u = ub + 16; ap1 = (u >= 0 && u < Lin) ? (xbb + (size_t)u * Cin) : zp; }
    { int u = ub + 32; ap2 = (u >= 0 && u < Lin) ? (xbb + (size_t)u * Cin) : zp; }
    { int u = ub + 48; ap3 = (u >= 0 && u < Lin) ? (xbb + (size_t)u * Cin) : zp; }
    const unsigned short* bp = wpb + (size_t)jj * CB * bstride;
    #pragma unroll 2
    for (int cb = 0; cb < CB; ++cb) {
      s16x8 bf = *(const s16x8*)(bp + (size_t)cb * bstride);
      s16x8 a0 = *(const s16x8*)(ap0 + cb * 32);
      s16x8 a1 = *(const s16x8*)(ap1 + cb * 32);
      s16x8 a2 = *(const s16x8*)(ap2 + cb * 32);
      s16x8 a3 = *(const s16x8*)(ap3 + cb * 32);
      acc0 = __builtin_amdgcn_mfma_f32_16x16x32_bf16(a0, bf, acc0, 0, 0, 0);
      acc1 = __builtin_amdgcn_mfma_f32_16x16x32_bf16(a1, bf, acc1, 0, 0, 0);
      acc2 = __builtin_amdgcn_mfma_f32_16x16x32_bf16(a2, bf, acc2, 0, 0, 0);
      acc3 = __builtin_amdgcn_mfma_f32_16x16x32_bf16(a3, bf, acc3, 0, 0, 0);
    }
  }

#define EPI(ACC, TI)                                                          \
  {                                                                           \
    _Pragma("unroll")                                                         \
    for (int reg = 0; reg < 4; ++reg) {                                       \
      int u  = u0 + (TI) * 16 + g * 4 + reg;                                  \
      int o  = S * u + p;                                                     \
      float v = elu_fast(ACC[reg] + bv);                                      \
      yb[((size_t)b * Lout + o) * Cout + (co0 + r)] = f2bf(v);                \
    }                                                                         \
  }
  EPI(acc0, 0) EPI(acc1, 1) EPI(acc2, 2) EPI(acc3, 3)
#undef EPI
}

// ---------------------------------------------------------------------------
// Final decoder layer from bf16 row-major input [B][65536][64]: tanh conv.
// ---------------------------------------------------------------------------
__global__ __launch_bounds__(256) void convt_final_bf16_k(
    const unsigned short* __restrict__ xb, const float* __restrict__ w,
    const float* __restrict__ bias, float* __restrict__ y)
{
  __shared__ float wl[64][16];
  for (int i = threadIdx.x; i < 64 * 15; i += 256) wl[i / 15][i % 15] = w[i];
  __syncthreads();
  const int b = blockIdx.y;
  const int o = blockIdx.x * 256 + threadIdx.x;
  float acc = 0.0f;
  #pragma unroll 1
  for (int m = 0; m < 15; ++m) {
    int i = o + 7 - m;
    if (i < 0 || i >= 65536) continue;
    const unsigned short* xp = xb + ((size_t)b * 65536 + i) * 64;
    #pragma unroll
    for (int c8 = 0; c8 < 8; ++c8) {
      s16x8 xv = *(const s16x8*)(xp + c8 * 8);
      #pragma unroll
      for (int k = 0; k < 8; ++k)
        acc = fmaf(wl[c8 * 8 + k][m], bf2f((unsigned short)xv[k]), acc);
    }
  }
  y[(size_t)b * 65536 + o] = tanhf(acc + bias[0]);
}

// ---------------------------------------------------------------------------
// recon |diff| partial reduce + final losses
// ---------------------------------------------------------------------------
__global__ __launch_bounds__(256) void absdiff_part_k(
    const float* __restrict__ a, const float* __restrict__ b, float* __restrict__ pr)
{
  __shared__ float cred[4];
  const int tid  = threadIdx.x;
  const int base = blockIdx.x * 2048;
  float s = 0.0f;
  for (int i = tid * 4; i < 2048; i += 1024) {
    float4 x = *(const float4*)(a + base + i);
    float4 y = *(const float4*)(b + base + i);
    s += fabsf(x.x - y.x) + fabsf(x.y - y.y) + fabsf(x.z - y.z) + fabsf(x.w - y.w);
  }
  #pragma unroll
  for (int off = 32; off; off >>= 1) s += __shfl_xor(s, off);
  const int lane = tid & 63, wv = tid >> 6;
  if (lane == 0) cred[wv] = s;
  __syncthreads();
  if (tid == 0) pr[blockIdx.x] = cred[0] + cred[1] + cred[2] + cred[3];
}

__global__ __launch_bounds__(256) void finalize_k(
    const float* __restrict__ pc, const float* __restrict__ pr, float* __restrict__ outp)
{
  __shared__ float red[4];
  const int tid = threadIdx.x;
  const int lane = tid & 63, wv = tid >> 6;

  float s = 0.0f;
  for (int i = tid; i < 8192; i += 256) s += pc[i];
  #pragma unroll
  for (int off = 32; off; off >>= 1) s += __shfl_xor(s, off);
  if (lane == 0) red[wv] = s;
  __syncthreads();
  if (tid == 0) outp[0] = 0.25f * (red[0] + red[1] + red[2] + red[3]) / 33554432.0f;
  __syncthreads();

  float s2 = 0.0f;
  if (tid < 64) {
    for (int i = tid; i < 256; i += 64) s2 += pr[i];
    #pragma unroll
    for (int off = 32; off; off >>= 1) s2 += __shfl_xor(s2, off);
    if (tid == 0) outp[1] = s2 / 524288.0f;
  }
}

// ---------------------------------------------------------------------------
extern "C" void kernel_launch(void* const* d_in, const int* in_sizes, int n_in,
                              void* d_out, int out_size, void* d_ws, size_t ws_size,
                              hipStream_t stream) {
  const float* wave = (const float*)d_in[0];
  const float* e1w = (const float*)d_in[1];  const float* e1b = (const float*)d_in[2];
  const float* e2w = (const float*)d_in[3];  const float* e2b = (const float*)d_in[4];
  const float* e3w = (const float*)d_in[5];  const float* e3b = (const float*)d_in[6];
  const float* e4w = (const float*)d_in[7];  const float* e4b = (const float*)d_in[8];
  const float* e5w = (const float*)d_in[9];  const float* e5b = (const float*)d_in[10];
  const float* cb  = (const float*)d_in[11];
  const float* d1w = (const float*)d_in[12]; const float* d1b = (const float*)d_in[13];
  const float* d2w = (const float*)d_in[14]; const float* d2b = (const float*)d_in[15];
  const float* d3w = (const float*)d_in[16]; const float* d3b = (const float*)d_in[17];
  const float* d4w = (const float*)d_in[18]; const float* d4b = (const float*)d_in[19];
  const float* d5w = (const float*)d_in[20]; const float* d5b = (const float*)d_in[21];

  float* out = (float*)d_out;
  float* recon  = out;                   // (8, 65536)
  float* qout   = out + 524288;          // (8, 8192, 512)
  float* codes  = out + 34078720;        // (8, 8192) as float
  float* losses = out + 34144256;        // [commitment, recon]

  float* A   = (float*)d_ws;             // 33554432 floats
  float* Bb  = A + 33554432;             // 33554432 floats
  float* t1  = Bb + 33554432;            // 65536
  float* cn  = t1 + 65536;               // 1024
  float* pc  = cn + 1024;                // 8192
  float* pr  = pc + 8192;                // 256
  float* cbp4 = pr + 256;                // 524288 (packed codebook, 2MB)

  // bf16 regions (reuse A/Bb halves):
  unsigned short* qb  = (unsigned short*)A;
  unsigned short* yb1 = (unsigned short*)Bb;
  unsigned short* yb2 = (unsigned short*)A;
  unsigned short* yb3 = (unsigned short*)(Bb + 16777216);
  unsigned short* yb4 = (unsigned short*)A;
  unsigned short* wsp   = (unsigned short*)(A + 16777216);
  unsigned short* zbuf  = wsp;
  unsigned short* wp1   = zbuf + 1024;
  unsigned short* wp2e  = wp1  + 1835008;
  unsigned short* wp2o  = wp2e + 917504;
  unsigned short* wp3e  = wp2o + 1048576;
  unsigned short* wp3o  = wp3e + 229376;
  unsigned short* wp4e  = wp3o + 262144;
  unsigned short* wp4o  = wp4e + 57344;

  dim3 blk(256);

  // ---- encoder (R14 champion; BIT-EXACT) ----
  conv1d_k<15,1,7,1><<<dim3(128,  4, 8), blk, 0, stream>>>(wave, e1w, e1b, A,   1,  64, 65536, 65536);
  conv1d_k<15,2,7,1><<<dim3( 64,  8, 8), blk, 0, stream>>>(A,    e2w, e2b, Bb, 64, 128, 65536, 32768);
  conv1d_k<15,2,7,1><<<dim3( 32, 16, 8), blk, 0, stream>>>(Bb,   e3w, e3b, A, 128, 256, 32768, 16384);
  conv1d_k<15,2,7,1><<<dim3( 16, 32, 8), blk, 0, stream>>>(A,    e4w, e4b, Bb,256, 512, 16384,  8192);
  conv1d_k< 7,1,3,0><<<dim3( 16, 32, 8), blk, 0, stream>>>(Bb,   e5w, e5b, A, 512, 512,  8192,  8192);

  // ---- VQ (BIT-EXACT expression; coalesced codebook layout) ----
  transpose_k<<<dim3(256, 16, 8), dim3(32, 8), 0, stream>>>(A, Bb, 512, 8192);
  rowsumsq_k<<<dim3(256), blk, 0, stream>>>(Bb, t1, 65536);
  rowsumsq_k<<<dim3(4),   blk, 0, stream>>>(cb, cn, 1024);
  prepack_cb_k<<<dim3(2048), blk, 0, stream>>>(cb, cbp4);
  vq_k<<<dim3(8192), blk, 0, stream>>>(Bb, cb, cbp4, t1, cn, qout, qb, codes, pc);

  // ---- decoder prep ----
  zero_zbuf_k<<<dim3(4), blk, 0, stream>>>(zbuf);
  prepack_w_k<<<dim3(7168), blk, 0, stream>>>(d1w, wp1, 512, 512, 7, 7, 0, 1);
  prepack_w_k<<<dim3(3584), blk, 0, stream>>>(d2w, wp2e, 512, 256, 15, 7, 1, 2);
  prepack_w_k<<<dim3(4096), blk, 0, stream>>>(d2w, wp2o, 512, 256, 15, 8, 0, 2);
  prepack_w_k<<<dim3( 896), blk, 0, stream>>>(d3w, wp3e, 256, 128, 15, 7, 1, 2);
  prepack_w_k<<<dim3(1024), blk, 0, stream>>>(d3w, wp3o, 256, 128, 15, 8, 0, 2);
  prepack_w_k<<<dim3( 224), blk, 0, stream>>>(d4w, wp4e, 128,  64, 15, 7, 1, 2);
  prepack_w_k<<<dim3( 256), blk, 0, stream>>>(d4w, wp4o, 128,  64, 15, 8, 0, 2);

  // ---- decoder (bf16 MFMA implicit GEMM; 4 u-tiles/wave) ----
  mfma_convt_k<<<dim3(32, 32, 8), blk, 0, stream>>>(qb,  wp1,  d1b, yb1, zbuf, 512, 512, 8192, 8192, 1, 0, 7, 3);
  mfma_convt_k<<<dim3(32, 16, 8), blk, 0, stream>>>(yb1, wp2e, d2b, yb2, zbuf, 512, 256, 8192, 16384, 2, 0, 7, 3);
  mfma_convt_k<<<dim3(32, 16, 8), blk, 0, stream>>>(yb1, wp2o, d2b, yb2, zbuf, 512, 256, 8192, 16384, 2, 1, 8, 4);
  mfma_convt_k<<<dim3(64,  8, 8), blk, 0, stream>>>(yb2, wp3e, d3b, yb3, zbuf, 256, 128, 16384, 32768, 2, 0, 7, 3);
  mfma_convt_k<<<dim3(64,  8, 8), blk, 0, stream>>>(yb2, wp3o, d3b, yb3, zbuf, 256, 128, 16384, 32768, 2, 1, 8, 4);
  mfma_convt_k<<<dim3(128, 4, 8), blk, 0, stream>>>(yb3, wp4e, d4b, yb4, zbuf, 128,  64, 32768, 65536, 2, 0, 7, 3);
  mfma_convt_k<<<dim3(128, 4, 8), blk, 0, stream>>>(yb3, wp4o, d4b, yb4, zbuf, 128,  64, 32768, 65536, 2, 1, 8, 4);
  convt_final_bf16_k<<<dim3(256, 8), blk, 0, stream>>>(yb4, d5w, d5b, recon);

  // ---- losses ----
  absdiff_part_k<<<dim3(256), blk, 0, stream>>>(recon, wave, pr);
  finalize_k<<<dim3(1), blk, 0, stream>>>(pc, pr, losses);
}